// Round 1
// baseline (7286.341 us; speedup 1.0000x reference)
//
#include <hip/hip_runtime.h>
#include <math.h>

#define T_SEQ 2048
#define D_MODEL 2048
#define N_HEADS 16
#define HDIM 128
#define EPSV 1e-6f

// ---------------------------------------------------------------------------
// RMSNorm: out = x / (sqrt(sum(x^2))/sqrt(D) + EPS) * w     (one block per row)
// ---------------------------------------------------------------------------
__global__ __launch_bounds__(256) void rmsnorm_kernel(
    const float* __restrict__ x, const float* __restrict__ w,
    float* __restrict__ out) {
  const int row = blockIdx.x;
  const float* xr = x + (size_t)row * D_MODEL;
  float* orow = out + (size_t)row * D_MODEL;

  float ss = 0.f;
#pragma unroll
  for (int it = 0; it < 2; ++it) {
    int i = threadIdx.x + it * 256;           // D/4 = 512 float4s
    float4 v = ((const float4*)xr)[i];
    ss += v.x * v.x + v.y * v.y + v.z * v.z + v.w * v.w;
  }
#pragma unroll
  for (int off = 32; off >= 1; off >>= 1) ss += __shfl_xor(ss, off, 64);

  __shared__ float red[4];
  if ((threadIdx.x & 63) == 0) red[threadIdx.x >> 6] = ss;
  __syncthreads();
  const float tot = red[0] + red[1] + red[2] + red[3];
  const float n = sqrtf(tot) * 0.022097086912079608f;  // * D^-0.5
  const float inv = 1.0f / (n + EPSV);

#pragma unroll
  for (int it = 0; it < 2; ++it) {
    int i = threadIdx.x + it * 256;
    float4 v = ((const float4*)xr)[i];
    float4 wv = ((const float4*)w)[i];
    float4 o;
    o.x = v.x * inv * wv.x;
    o.y = v.y * inv * wv.y;
    o.z = v.z * inv * wv.z;
    o.w = v.w * inv * wv.w;
    ((float4*)orow)[i] = o;
  }
}

// ---------------------------------------------------------------------------
// fp32 SGEMM: C[M,N] = act(A[M,K] @ W[K,N] + bias) (+ residual)
// BM=BN=128, BK=32, 256 threads, 8x8 micro-tile (split 4+4 to keep LDS reads
// <=2-way bank aliased: fragment cols {tx*4, 64+tx*4}, rows {ty*4, 64+ty*4}).
// ACT: 0 = none, 1 = silu.
// ---------------------------------------------------------------------------
template <int ACT, bool RES>
__global__ __launch_bounds__(256) void gemm_kernel(
    const float* __restrict__ A, const float* __restrict__ W,
    const float* __restrict__ bias, const float* __restrict__ res,
    float* __restrict__ C, int M, int N, int K) {
  __shared__ float As[32][132];  // [k][m], +4 pad spreads transpose-store banks
  __shared__ float Bs[32][128];  // [k][n]

  const int tid = threadIdx.x;
  const int tx = tid & 15, ty = tid >> 4;
  const int bm = blockIdx.y, bn = blockIdx.x;

  const int arow = tid >> 3;          // 0..31
  const int acol4 = (tid & 7) << 2;   // 0..28
  const int brow = tid >> 5;          // 0..7
  const int bcol4 = (tid & 31) << 2;  // 0..124

  const float* Ag = A + (size_t)(bm * 128 + arow) * K + acol4;
  const float* Wg = W + (size_t)brow * N + bn * 128 + bcol4;

  float acc[8][8];
#pragma unroll
  for (int i = 0; i < 8; ++i)
#pragma unroll
    for (int j = 0; j < 8; ++j) acc[i][j] = 0.f;

  for (int k0 = 0; k0 < K; k0 += 32) {
    float4 av[4], bv[4];
#pragma unroll
    for (int p = 0; p < 4; ++p) av[p] = *(const float4*)(Ag + (size_t)(p * 32) * K);
#pragma unroll
    for (int p = 0; p < 4; ++p) bv[p] = *(const float4*)(Wg + (size_t)(p * 8) * N);
    __syncthreads();  // previous iteration's compute done before overwrite
#pragma unroll
    for (int p = 0; p < 4; ++p) {
      const int r = arow + p * 32;
      As[acol4 + 0][r] = av[p].x;
      As[acol4 + 1][r] = av[p].y;
      As[acol4 + 2][r] = av[p].z;
      As[acol4 + 3][r] = av[p].w;
    }
#pragma unroll
    for (int p = 0; p < 4; ++p) *(float4*)&Bs[brow + p * 8][bcol4] = bv[p];
    __syncthreads();
    Ag += 32;
    Wg += (size_t)32 * N;

#pragma unroll
    for (int k = 0; k < 32; ++k) {
      const float4 t0 = *(const float4*)&As[k][ty * 4];
      const float4 t1 = *(const float4*)&As[k][64 + ty * 4];
      const float4 u0 = *(const float4*)&Bs[k][tx * 4];
      const float4 u1 = *(const float4*)&Bs[k][64 + tx * 4];
      const float a[8] = {t0.x, t0.y, t0.z, t0.w, t1.x, t1.y, t1.z, t1.w};
      const float b[8] = {u0.x, u0.y, u0.z, u0.w, u1.x, u1.y, u1.z, u1.w};
#pragma unroll
      for (int i = 0; i < 8; ++i)
#pragma unroll
        for (int j = 0; j < 8; ++j) acc[i][j] += a[i] * b[j];
    }
  }

  // epilogue
#pragma unroll
  for (int ih = 0; ih < 2; ++ih) {
#pragma unroll
    for (int ii = 0; ii < 4; ++ii) {
      const int i = ih * 4 + ii;
      const int row = bm * 128 + ih * 64 + ty * 4 + ii;
#pragma unroll
      for (int jh = 0; jh < 2; ++jh) {
        const int col = bn * 128 + jh * 64 + tx * 4;
        float4 v;
        v.x = acc[i][jh * 4 + 0];
        v.y = acc[i][jh * 4 + 1];
        v.z = acc[i][jh * 4 + 2];
        v.w = acc[i][jh * 4 + 3];
        const float4 bb = *(const float4*)&bias[col];
        v.x += bb.x; v.y += bb.y; v.z += bb.z; v.w += bb.w;
        if (ACT == 1) {  // silu
          v.x = v.x / (1.f + expf(-v.x));
          v.y = v.y / (1.f + expf(-v.y));
          v.z = v.z / (1.f + expf(-v.z));
          v.w = v.w / (1.f + expf(-v.w));
        }
        if (RES) {
          const float4 rv = *(const float4*)&res[(size_t)row * N + col];
          v.x += rv.x; v.y += rv.y; v.z += rv.z; v.w += rv.w;
        }
        *(float4*)&C[(size_t)row * N + col] = v;
      }
    }
  }
}

// ---------------------------------------------------------------------------
// RoPE in-place on qkv[B,T,3D] (q and k halves). Replicates reference f32
// rounding of theta = t * 10000^(-i/64), evaluates sin/cos in double.
// ---------------------------------------------------------------------------
__global__ __launch_bounds__(256) void rope_kernel(float* __restrict__ qkv) {
  const int p = blockIdx.x * 256 + threadIdx.x;  // grid sized exactly
  const int i = p & 63;
  const int h = (p >> 6) & (N_HEADS - 1);
  const int t = (p >> 10) & (T_SEQ - 1);
  const int b = p >> 21;
  const size_t base = ((size_t)(b * T_SEQ + t)) * (3 * D_MODEL) + h * HDIM + i;

  const float ratef = (float)pow(10000.0, -(double)i / 64.0);
  const float theta = (float)t * ratef;  // f32 rounding as in reference
  const double th = (double)theta;
  const float c = (float)cos(th);
  const float s = (float)sin(th);

  const float q1 = qkv[base], q2 = qkv[base + 64];
  qkv[base] = q1 * c - q2 * s;
  qkv[base + 64] = q1 * s + q2 * c;
  const float k1 = qkv[base + D_MODEL], k2 = qkv[base + D_MODEL + 64];
  qkv[base + D_MODEL] = k1 * c - k2 * s;
  qkv[base + D_MODEL + 64] = k1 * s + k2 * c;
}

// ---------------------------------------------------------------------------
// Flash attention (causal), fp32. Block = (q-tile of 64) x (b,h).
// 256 threads as 16x16: score micro-tile 4x4, O cols {tx*4, 64+tx*4}.
// ---------------------------------------------------------------------------
__global__ __launch_bounds__(256) void attn_kernel(
    const float* __restrict__ qkv, float* __restrict__ out) {
  __shared__ float Qs[64][132];
  __shared__ float Ks[64][132];
  __shared__ float Vs[64][132];
  __shared__ float Ps[64][68];

  const int qt = blockIdx.x;
  const int b = blockIdx.y >> 4;
  const int h = blockIdx.y & (N_HEADS - 1);
  const int tid = threadIdx.x;
  const int tx = tid & 15, ty = tid >> 4;

  const float* base = qkv + (size_t)b * T_SEQ * (3 * D_MODEL) + h * HDIM;
  const int lrow = tid >> 5;          // 0..7
  const int lcol4 = (tid & 31) << 2;  // 0..124

#pragma unroll
  for (int p = 0; p < 8; ++p) {
    const int r = lrow + p * 8;
    *(float4*)&Qs[r][lcol4] =
        *(const float4*)(base + (size_t)(qt * 64 + r) * (3 * D_MODEL) + lcol4);
  }

  float m[4], l[4];
  float4 Oa[4][2];
#pragma unroll
  for (int i = 0; i < 4; ++i) {
    m[i] = -INFINITY;
    l[i] = 0.f;
    Oa[i][0] = make_float4(0.f, 0.f, 0.f, 0.f);
    Oa[i][1] = make_float4(0.f, 0.f, 0.f, 0.f);
  }

  for (int kt = 0; kt <= qt; ++kt) {
    __syncthreads();  // prev PV reads done before K/V/P overwrite
#pragma unroll
    for (int p = 0; p < 8; ++p) {
      const int r = lrow + p * 8;
      const float* g = base + (size_t)(kt * 64 + r) * (3 * D_MODEL) + lcol4;
      *(float4*)&Ks[r][lcol4] = *(const float4*)(g + D_MODEL);
      *(float4*)&Vs[r][lcol4] = *(const float4*)(g + 2 * D_MODEL);
    }
    __syncthreads();

    float s[4][4];
#pragma unroll
    for (int i = 0; i < 4; ++i)
#pragma unroll
      for (int j = 0; j < 4; ++j) s[i][j] = 0.f;

#pragma unroll 8
    for (int d4 = 0; d4 < 32; ++d4) {
      float4 q[4], kk[4];
#pragma unroll
      for (int i = 0; i < 4; ++i) q[i] = *(const float4*)&Qs[ty * 4 + i][d4 * 4];
#pragma unroll
      for (int j = 0; j < 4; ++j) kk[j] = *(const float4*)&Ks[tx * 4 + j][d4 * 4];
#pragma unroll
      for (int i = 0; i < 4; ++i)
#pragma unroll
        for (int j = 0; j < 4; ++j)
          s[i][j] += q[i].x * kk[j].x + q[i].y * kk[j].y + q[i].z * kk[j].z +
                     q[i].w * kk[j].w;
    }

    const float scale = 0.08838834764831845f;  // HD^-0.5
    const int qr0 = qt * 64 + ty * 4;
    const int kc0 = kt * 64 + tx * 4;
    float alpha[4];
#pragma unroll
    for (int i = 0; i < 4; ++i) {
      float rm = -INFINITY;
#pragma unroll
      for (int j = 0; j < 4; ++j) {
        float v = s[i][j] * scale;
        if (kc0 + j > qr0 + i) v = -INFINITY;  // causal mask
        s[i][j] = v;
        rm = fmaxf(rm, v);
      }
      rm = fmaxf(rm, __shfl_xor(rm, 1, 64));
      rm = fmaxf(rm, __shfl_xor(rm, 2, 64));
      rm = fmaxf(rm, __shfl_xor(rm, 4, 64));
      rm = fmaxf(rm, __shfl_xor(rm, 8, 64));
      const float mnew = fmaxf(m[i], rm);
      const float a = expf(m[i] - mnew);  // first tile: exp(-inf)=0
      float rs = 0.f;
#pragma unroll
      for (int j = 0; j < 4; ++j) {
        const float pv = expf(s[i][j] - mnew);
        s[i][j] = pv;
        rs += pv;
      }
      rs += __shfl_xor(rs, 1, 64);
      rs += __shfl_xor(rs, 2, 64);
      rs += __shfl_xor(rs, 4, 64);
      rs += __shfl_xor(rs, 8, 64);
      l[i] = l[i] * a + rs;
      m[i] = mnew;
      alpha[i] = a;
    }

#pragma unroll
    for (int i = 0; i < 4; ++i) {
      Oa[i][0].x *= alpha[i]; Oa[i][0].y *= alpha[i];
      Oa[i][0].z *= alpha[i]; Oa[i][0].w *= alpha[i];
      Oa[i][1].x *= alpha[i]; Oa[i][1].y *= alpha[i];
      Oa[i][1].z *= alpha[i]; Oa[i][1].w *= alpha[i];
      *(float4*)&Ps[ty * 4 + i][tx * 4] =
          make_float4(s[i][0], s[i][1], s[i][2], s[i][3]);
    }
    __syncthreads();

#pragma unroll 8
    for (int j = 0; j < 64; ++j) {
      const float4 v0 = *(const float4*)&Vs[j][tx * 4];
      const float4 v1 = *(const float4*)&Vs[j][64 + tx * 4];
#pragma unroll
      for (int i = 0; i < 4; ++i) {
        const float pv = Ps[ty * 4 + i][j];
        Oa[i][0].x += pv * v0.x; Oa[i][0].y += pv * v0.y;
        Oa[i][0].z += pv * v0.z; Oa[i][0].w += pv * v0.w;
        Oa[i][1].x += pv * v1.x; Oa[i][1].y += pv * v1.y;
        Oa[i][1].z += pv * v1.z; Oa[i][1].w += pv * v1.w;
      }
    }
  }

  // epilogue: O / l  -> out[B,T,D] at (b, t, h*128 + col)
#pragma unroll
  for (int i = 0; i < 4; ++i) {
    const float inv = 1.f / l[i];
    const int t = qt * 64 + ty * 4 + i;
    float* orow = out + (size_t)(b * T_SEQ + t) * D_MODEL + h * HDIM;
    float4 o0 = Oa[i][0], o1 = Oa[i][1];
    o0.x *= inv; o0.y *= inv; o0.z *= inv; o0.w *= inv;
    o1.x *= inv; o1.y *= inv; o1.z *= inv; o1.w *= inv;
    *(float4*)&orow[tx * 4] = o0;
    *(float4*)&orow[64 + tx * 4] = o1;
  }
}

// ---------------------------------------------------------------------------
extern "C" void kernel_launch(void* const* d_in, const int* in_sizes, int n_in,
                              void* d_out, int out_size, void* d_ws,
                              size_t ws_size, hipStream_t stream) {
  const float* x       = (const float*)d_in[0];
  // d_in[1] = mask (causal, known analytically) — unused
  const float* w_norm1 = (const float*)d_in[2];
  const float* w_qkv   = (const float*)d_in[3];
  const float* b_qkv   = (const float*)d_in[4];
  const float* w_proj  = (const float*)d_in[5];
  const float* b_proj  = (const float*)d_in[6];
  const float* w_norm2 = (const float*)d_in[7];
  const float* w_fc1   = (const float*)d_in[8];
  const float* b_fc1   = (const float*)d_in[9];
  const float* w_fc2   = (const float*)d_in[10];
  const float* b_fc2   = (const float*)d_in[11];
  float* out = (float*)d_out;

  const size_t M = (size_t)2 * T_SEQ;  // 4096 rows
  float* qkvb = (float*)d_ws;                       // M*6144 = 96 MB
  float* bufA = qkvb + M * (3 * D_MODEL);           // M*2048 = 32 MB
  float* fc1b = bufA + M * D_MODEL;                 // M*8192 = 128 MB
  // d_out doubles as x2 (post-attention residual), 32 MB

  // 1. h = rmsnorm(x, w_norm1)
  rmsnorm_kernel<<<4096, 256, 0, stream>>>(x, w_norm1, bufA);
  // 2. qkv = h @ w_qkv + b_qkv
  gemm_kernel<0, false><<<dim3(48, 32), 256, 0, stream>>>(
      bufA, w_qkv, b_qkv, nullptr, qkvb, 4096, 6144, 2048);
  // 3. RoPE in-place on q,k
  rope_kernel<<<16384, 256, 0, stream>>>(qkvb);
  // 4. y = attention(q,k,v)  -> bufA [B,T,D]
  attn_kernel<<<dim3(32, 32), 256, 0, stream>>>(qkvb, bufA);
  // 5. x2 = x + y @ w_proj + b_proj  -> d_out
  gemm_kernel<0, true><<<dim3(16, 32), 256, 0, stream>>>(
      bufA, w_proj, b_proj, x, out, 4096, 2048, 2048);
  // 6. h2 = rmsnorm(x2, w_norm2)
  rmsnorm_kernel<<<4096, 256, 0, stream>>>(out, w_norm2, bufA);
  // 7. f = silu(h2 @ w_fc1 + b_fc1)
  gemm_kernel<1, false><<<dim3(64, 32), 256, 0, stream>>>(
      bufA, w_fc1, b_fc1, nullptr, fc1b, 4096, 8192, 2048);
  // 8. out = x2 + f @ w_fc2 + b_fc2  (in-place residual: same-thread r-then-w)
  gemm_kernel<0, true><<<dim3(16, 32), 256, 0, stream>>>(
      fc1b, w_fc2, b_fc2, out, out, 4096, 2048, 8192);
}

// Round 2
// 3753.207 us; speedup vs baseline: 1.9414x; 1.9414x over previous
//
#include <hip/hip_runtime.h>
#include <math.h>

typedef unsigned short u16;
typedef unsigned int u32;
typedef __attribute__((ext_vector_type(8))) short short8v;
typedef __attribute__((ext_vector_type(4))) float float4v;

#define T_SEQ 2048
#define D_MODEL 2048
#define N_HEADS 16
#define EPSV 1e-6f
#define MROWS 4096

// ---------------- small helpers ----------------
__device__ __forceinline__ u16 f2bf(float f) {  // RNE float -> bf16 bits
  union { float f; u32 u; } v; v.f = f;
  u32 r = v.u + 0x7fffu + ((v.u >> 16) & 1u);
  return (u16)(r >> 16);
}
__device__ __forceinline__ float bf2f(u16 h) {
  union { u32 u; float f; } v; v.u = ((u32)h) << 16;
  return v.f;
}
__device__ __forceinline__ void gl16(const void* g, void* l) {
  __builtin_amdgcn_global_load_lds(
      (const __attribute__((address_space(1))) void*)g,
      (__attribute__((address_space(3))) void*)l, 16, 0, 0);
}

// ---------------------------------------------------------------------------
// RMSNorm -> split bf16 (hi, lo). One block per row.
// ---------------------------------------------------------------------------
__global__ __launch_bounds__(256) void rmsnorm_split_kernel(
    const float* __restrict__ x, const float* __restrict__ w,
    u16* __restrict__ oh, u16* __restrict__ ol) {
  const int row = blockIdx.x;
  const float* xr = x + (size_t)row * D_MODEL;

  float ss = 0.f;
#pragma unroll
  for (int it = 0; it < 2; ++it) {
    int i = threadIdx.x + it * 256;
    float4 v = ((const float4*)xr)[i];
    ss += v.x * v.x + v.y * v.y + v.z * v.z + v.w * v.w;
  }
#pragma unroll
  for (int off = 32; off >= 1; off >>= 1) ss += __shfl_xor(ss, off, 64);
  __shared__ float red[4];
  if ((threadIdx.x & 63) == 0) red[threadIdx.x >> 6] = ss;
  __syncthreads();
  const float tot = red[0] + red[1] + red[2] + red[3];
  const float n = sqrtf(tot) * 0.022097086912079608f;
  const float inv = 1.0f / (n + EPSV);

  u16* ohr = oh + (size_t)row * D_MODEL;
  u16* olr = ol + (size_t)row * D_MODEL;
#pragma unroll
  for (int it = 0; it < 2; ++it) {
    int i = threadIdx.x + it * 256;
    float4 v = ((const float4*)xr)[i];
    float4 wv = ((const float4*)w)[i];
    float o[4] = {v.x * inv * wv.x, v.y * inv * wv.y, v.z * inv * wv.z,
                  v.w * inv * wv.w};
    ushort4 h4, l4;
    h4.x = f2bf(o[0]); l4.x = f2bf(o[0] - bf2f(h4.x));
    h4.y = f2bf(o[1]); l4.y = f2bf(o[1] - bf2f(h4.y));
    h4.z = f2bf(o[2]); l4.z = f2bf(o[2] - bf2f(h4.z));
    h4.w = f2bf(o[3]); l4.w = f2bf(o[3] - bf2f(h4.w));
    ((ushort4*)ohr)[i] = h4;
    ((ushort4*)olr)[i] = l4;
  }
}

// ---------------------------------------------------------------------------
// Weight split + transpose: W[K][N] f32 -> Th[N][K], Tl[N][K] bf16
// block (32,8), 32x32 tile
// ---------------------------------------------------------------------------
__global__ __launch_bounds__(256) void splitT_kernel(
    const float* __restrict__ W, u16* __restrict__ Th, u16* __restrict__ Tl,
    int K, int N) {
  __shared__ float tile[32][33];
  const int tx = threadIdx.x, ty = threadIdx.y;
  const int n0 = blockIdx.x * 32, k0 = blockIdx.y * 32;
#pragma unroll
  for (int i = 0; i < 4; ++i)
    tile[ty + i * 8][tx] = W[(size_t)(k0 + ty + i * 8) * N + n0 + tx];
  __syncthreads();
#pragma unroll
  for (int i = 0; i < 4; ++i) {
    const float v = tile[tx][ty + i * 8];
    const int n = n0 + ty + i * 8, k = k0 + tx;
    const u16 h = f2bf(v);
    Th[(size_t)n * K + k] = h;
    Tl[(size_t)n * K + k] = f2bf(v - bf2f(h));
  }
}

// ---------------------------------------------------------------------------
// Split-bf16 MFMA GEMM: C[M,N] = A(M,K) * Wt(N,K)^T over K' = 3K phases
// (Ah*Bh + Al*Bh + Ah*Bl). 128x128 tile, BK=32, 4 waves, 16x16x32 bf16 MFMA.
// OUT: 0 = f32, 1 = f32 + residual, 2 = silu -> split bf16 (Ch, Cl)
// ---------------------------------------------------------------------------
template <int OUT>
__global__ __launch_bounds__(256) void mgemm_kernel(
    const u16* __restrict__ Ah, const u16* __restrict__ Al,
    const u16* __restrict__ Bh, const u16* __restrict__ Bl,
    const float* __restrict__ bias, const float* __restrict__ res,
    float* __restrict__ C, u16* __restrict__ Ch, u16* __restrict__ Cl,
    int N, int K) {
  __shared__ u16 LA[2][4096];
  __shared__ u16 LB[2][4096];

  const int tid = threadIdx.x;
  const int lane = tid & 63;
  const int wv = tid >> 6;
  const int wr = wv >> 1, wc = wv & 1;
  const int bm = blockIdx.y, bn = blockIdx.x;

  // staging: per wave 2 chunks of 16 rows; lane -> (row = lane/4, col8 = lane%4)
  const int srow = lane >> 2;
  const int scol = (lane & 3) << 3;
  const int c0 = wv * 2, c1 = c0 + 1;

  const size_t aoff0 = (size_t)(bm * 128 + c0 * 16 + srow) * K + scol;
  const size_t aoff1 = (size_t)(bm * 128 + c1 * 16 + srow) * K + scol;
  const size_t boff0 = (size_t)(bn * 128 + c0 * 16 + srow) * K + scol;
  const size_t boff1 = (size_t)(bn * 128 + c1 * 16 + srow) * K + scol;

  const u16* APH[3] = {Ah, Al, Ah};
  const u16* BPH[3] = {Bh, Bh, Bl};
  const int S = K >> 5;
  const int S3 = 3 * S;

  float4v acc[4][4];
  const float4v zf = {0.f, 0.f, 0.f, 0.f};
#pragma unroll
  for (int i = 0; i < 4; ++i)
#pragma unroll
    for (int j = 0; j < 4; ++j) acc[i][j] = zf;

  auto STAGE = [&](int buf, int step) {
    const int ph = (step >= S) + (step >= 2 * S);
    const size_t kk = (size_t)(step - ph * S) << 5;
    const u16* ab = APH[ph];
    const u16* bb = BPH[ph];
    gl16(ab + aoff0 + kk, &LA[buf][c0 << 9]);
    gl16(ab + aoff1 + kk, &LA[buf][c1 << 9]);
    gl16(bb + boff0 + kk, &LB[buf][c0 << 9]);
    gl16(bb + boff1 + kk, &LB[buf][c1 << 9]);
  };

  const int l15 = lane & 15;
  const int kq = lane >> 4;
  const int aoffc = (wr * 64 + l15) * 32 + kq * 8;
  const int boffc = (wc * 64 + l15) * 32 + kq * 8;

  auto COMPUTE = [&](int buf) {
    short8v bfr[4];
#pragma unroll
    for (int ni = 0; ni < 4; ++ni)
      bfr[ni] = *(const short8v*)&LB[buf][boffc + ni * 512];
#pragma unroll
    for (int mi = 0; mi < 4; ++mi) {
      const short8v afr = *(const short8v*)&LA[buf][aoffc + mi * 512];
#pragma unroll
      for (int ni = 0; ni < 4; ++ni)
        acc[mi][ni] = __builtin_amdgcn_mfma_f32_16x16x32_bf16(
            afr, bfr[ni], acc[mi][ni], 0, 0, 0);
    }
  };

  STAGE(0, 0);
  __syncthreads();
  for (int step = 0; step < S3 - 1; ++step) {
    const int cur = step & 1;
    STAGE(cur ^ 1, step + 1);
    COMPUTE(cur);
    __syncthreads();
  }
  COMPUTE((S3 - 1) & 1);

  // epilogue: D row = (lane>>4)*4 + reg, col = lane&15
  const int rsub = kq * 4;
#pragma unroll
  for (int mi = 0; mi < 4; ++mi) {
#pragma unroll
    for (int ni = 0; ni < 4; ++ni) {
      const int col = bn * 128 + wc * 64 + ni * 16 + l15;
      const float bb = bias[col];
      const float4v v = acc[mi][ni];
#pragma unroll
      for (int r = 0; r < 4; ++r) {
        const int row = bm * 128 + wr * 64 + mi * 16 + rsub + r;
        float val = v[r] + bb;
        if (OUT == 1) val += res[(size_t)row * N + col];
        if (OUT == 2) {
          const float sv = val / (1.f + expf(-val));
          const u16 hh = f2bf(sv);
          Ch[(size_t)row * N + col] = hh;
          Cl[(size_t)row * N + col] = f2bf(sv - bf2f(hh));
        } else {
          C[(size_t)row * N + col] = val;
        }
      }
    }
  }
}

// ---------------------------------------------------------------------------
// RoPE cos/sin table (double-precision trig once), then cheap apply.
// ---------------------------------------------------------------------------
__global__ __launch_bounds__(256) void rope_table_kernel(
    float* __restrict__ ct, float* __restrict__ st) {
  const int p = blockIdx.x * 256 + threadIdx.x;  // 2048*64
  const int i = p & 63;
  const int t = p >> 6;
  const float ratef = (float)pow(10000.0, -(double)i / 64.0);
  const float theta = (float)t * ratef;
  ct[p] = (float)cos((double)theta);
  st[p] = (float)sin((double)theta);
}

__global__ __launch_bounds__(256) void rope_apply_kernel(
    float* __restrict__ qkv, const float* __restrict__ ct,
    const float* __restrict__ st) {
  const int p = blockIdx.x * 256 + threadIdx.x;
  const int i = p & 63;
  const int h = (p >> 6) & (N_HEADS - 1);
  const int t = (p >> 10) & (T_SEQ - 1);
  const int b = p >> 21;
  const size_t base =
      ((size_t)(b * T_SEQ + t)) * (3 * D_MODEL) + h * 128 + i;
  const float c = ct[(t << 6) + i];
  const float s = st[(t << 6) + i];

  const float q1 = qkv[base], q2 = qkv[base + 64];
  qkv[base] = q1 * c - q2 * s;
  qkv[base + 64] = q1 * s + q2 * c;
  const float k1 = qkv[base + D_MODEL], k2 = qkv[base + D_MODEL + 64];
  qkv[base + D_MODEL] = k1 * c - k2 * s;
  qkv[base + D_MODEL + 64] = k1 * s + k2 * c;
}

// ---------------------------------------------------------------------------
// Flash attention (causal), fp32 — output split to bf16 hi/lo
// ---------------------------------------------------------------------------
__global__ __launch_bounds__(256) void attn_kernel(
    const float* __restrict__ qkv, u16* __restrict__ yh,
    u16* __restrict__ yl) {
  __shared__ float Qs[64][132];
  __shared__ float Ks[64][132];
  __shared__ float Vs[64][132];
  __shared__ float Ps[64][68];

  const int qt = blockIdx.x;
  const int b = blockIdx.y >> 4;
  const int h = blockIdx.y & (N_HEADS - 1);
  const int tid = threadIdx.x;
  const int tx = tid & 15, ty = tid >> 4;

  const float* base = qkv + (size_t)b * T_SEQ * (3 * D_MODEL) + h * 128;
  const int lrow = tid >> 5;
  const int lcol4 = (tid & 31) << 2;

#pragma unroll
  for (int p = 0; p < 8; ++p) {
    const int r = lrow + p * 8;
    *(float4*)&Qs[r][lcol4] =
        *(const float4*)(base + (size_t)(qt * 64 + r) * (3 * D_MODEL) + lcol4);
  }

  float m[4], l[4];
  float4 Oa[4][2];
#pragma unroll
  for (int i = 0; i < 4; ++i) {
    m[i] = -INFINITY;
    l[i] = 0.f;
    Oa[i][0] = make_float4(0.f, 0.f, 0.f, 0.f);
    Oa[i][1] = make_float4(0.f, 0.f, 0.f, 0.f);
  }

  for (int kt = 0; kt <= qt; ++kt) {
    __syncthreads();
#pragma unroll
    for (int p = 0; p < 8; ++p) {
      const int r = lrow + p * 8;
      const float* g = base + (size_t)(kt * 64 + r) * (3 * D_MODEL) + lcol4;
      *(float4*)&Ks[r][lcol4] = *(const float4*)(g + D_MODEL);
      *(float4*)&Vs[r][lcol4] = *(const float4*)(g + 2 * D_MODEL);
    }
    __syncthreads();

    float s[4][4];
#pragma unroll
    for (int i = 0; i < 4; ++i)
#pragma unroll
      for (int j = 0; j < 4; ++j) s[i][j] = 0.f;

#pragma unroll 8
    for (int d4 = 0; d4 < 32; ++d4) {
      float4 q[4], kk[4];
#pragma unroll
      for (int i = 0; i < 4; ++i) q[i] = *(const float4*)&Qs[ty * 4 + i][d4 * 4];
#pragma unroll
      for (int j = 0; j < 4; ++j) kk[j] = *(const float4*)&Ks[tx * 4 + j][d4 * 4];
#pragma unroll
      for (int i = 0; i < 4; ++i)
#pragma unroll
        for (int j = 0; j < 4; ++j)
          s[i][j] += q[i].x * kk[j].x + q[i].y * kk[j].y + q[i].z * kk[j].z +
                     q[i].w * kk[j].w;
    }

    const float scale = 0.08838834764831845f;
    const int qr0 = qt * 64 + ty * 4;
    const int kc0 = kt * 64 + tx * 4;
    float alpha[4];
#pragma unroll
    for (int i = 0; i < 4; ++i) {
      float rm = -INFINITY;
#pragma unroll
      for (int j = 0; j < 4; ++j) {
        float v = s[i][j] * scale;
        if (kc0 + j > qr0 + i) v = -INFINITY;
        s[i][j] = v;
        rm = fmaxf(rm, v);
      }
      rm = fmaxf(rm, __shfl_xor(rm, 1, 64));
      rm = fmaxf(rm, __shfl_xor(rm, 2, 64));
      rm = fmaxf(rm, __shfl_xor(rm, 4, 64));
      rm = fmaxf(rm, __shfl_xor(rm, 8, 64));
      const float mnew = fmaxf(m[i], rm);
      const float a = expf(m[i] - mnew);
      float rs = 0.f;
#pragma unroll
      for (int j = 0; j < 4; ++j) {
        const float pv = expf(s[i][j] - mnew);
        s[i][j] = pv;
        rs += pv;
      }
      rs += __shfl_xor(rs, 1, 64);
      rs += __shfl_xor(rs, 2, 64);
      rs += __shfl_xor(rs, 4, 64);
      rs += __shfl_xor(rs, 8, 64);
      l[i] = l[i] * a + rs;
      m[i] = mnew;
      alpha[i] = a;
    }

#pragma unroll
    for (int i = 0; i < 4; ++i) {
      Oa[i][0].x *= alpha[i]; Oa[i][0].y *= alpha[i];
      Oa[i][0].z *= alpha[i]; Oa[i][0].w *= alpha[i];
      Oa[i][1].x *= alpha[i]; Oa[i][1].y *= alpha[i];
      Oa[i][1].z *= alpha[i]; Oa[i][1].w *= alpha[i];
      *(float4*)&Ps[ty * 4 + i][tx * 4] =
          make_float4(s[i][0], s[i][1], s[i][2], s[i][3]);
    }
    __syncthreads();

#pragma unroll 8
    for (int j = 0; j < 64; ++j) {
      const float4 v0 = *(const float4*)&Vs[j][tx * 4];
      const float4 v1 = *(const float4*)&Vs[j][64 + tx * 4];
#pragma unroll
      for (int i = 0; i < 4; ++i) {
        const float pv = Ps[ty * 4 + i][j];
        Oa[i][0].x += pv * v0.x; Oa[i][0].y += pv * v0.y;
        Oa[i][0].z += pv * v0.z; Oa[i][0].w += pv * v0.w;
        Oa[i][1].x += pv * v1.x; Oa[i][1].y += pv * v1.y;
        Oa[i][1].z += pv * v1.z; Oa[i][1].w += pv * v1.w;
      }
    }
  }

#pragma unroll
  for (int i = 0; i < 4; ++i) {
    const float inv = 1.f / l[i];
    const int t = qt * 64 + ty * 4 + i;
    const size_t ob = (size_t)(b * T_SEQ + t) * D_MODEL + h * 128;
    float4 o0 = Oa[i][0], o1 = Oa[i][1];
    o0.x *= inv; o0.y *= inv; o0.z *= inv; o0.w *= inv;
    o1.x *= inv; o1.y *= inv; o1.z *= inv; o1.w *= inv;
    ushort4 h4, l4;
    h4.x = f2bf(o0.x); l4.x = f2bf(o0.x - bf2f(h4.x));
    h4.y = f2bf(o0.y); l4.y = f2bf(o0.y - bf2f(h4.y));
    h4.z = f2bf(o0.z); l4.z = f2bf(o0.z - bf2f(h4.z));
    h4.w = f2bf(o0.w); l4.w = f2bf(o0.w - bf2f(h4.w));
    *(ushort4*)&yh[ob + tx * 4] = h4;
    *(ushort4*)&yl[ob + tx * 4] = l4;
    h4.x = f2bf(o1.x); l4.x = f2bf(o1.x - bf2f(h4.x));
    h4.y = f2bf(o1.y); l4.y = f2bf(o1.y - bf2f(h4.y));
    h4.z = f2bf(o1.z); l4.z = f2bf(o1.z - bf2f(h4.z));
    h4.w = f2bf(o1.w); l4.w = f2bf(o1.w - bf2f(h4.w));
    *(ushort4*)&yh[ob + 64 + tx * 4] = h4;
    *(ushort4*)&yl[ob + 64 + tx * 4] = l4;
  }
}

// ---------------------------------------------------------------------------
extern "C" void kernel_launch(void* const* d_in, const int* in_sizes, int n_in,
                              void* d_out, int out_size, void* d_ws,
                              size_t ws_size, hipStream_t stream) {
  const float* x       = (const float*)d_in[0];
  const float* w_norm1 = (const float*)d_in[2];
  const float* w_qkv   = (const float*)d_in[3];
  const float* b_qkv   = (const float*)d_in[4];
  const float* w_proj  = (const float*)d_in[5];
  const float* b_proj  = (const float*)d_in[6];
  const float* w_norm2 = (const float*)d_in[7];
  const float* w_fc1   = (const float*)d_in[8];
  const float* b_fc1   = (const float*)d_in[9];
  const float* w_fc2   = (const float*)d_in[10];
  const float* b_fc2   = (const float*)d_in[11];
  float* out = (float*)d_out;

  char* wsb = (char*)d_ws;
  // [0, 128MiB): qkv f32 (96MiB) OR fc1 split bf16 (64+64MiB) — disjoint lifetimes
  float* qkvb = (float*)wsb;
  u16* fc1h = (u16*)wsb;
  u16* fc1l = fc1h + (size_t)MROWS * 8192;
  // [128, 160MiB): activation split (h1 -> y -> h2)
  u16* ah = (u16*)(wsb + 128ull * 1024 * 1024);
  u16* al = ah + (size_t)MROWS * 2048;
  // [160, 224MiB): weight split+transpose scratch (max 8192x2048 x2)
  u16* wth = (u16*)(wsb + 160ull * 1024 * 1024);
  u16* wtl = wth + 16777216ull;
  // [224, 225MiB): rope tables
  float* ct = (float*)(wsb + 224ull * 1024 * 1024);
  float* st = ct + 131072;

  // rope tables (cheap, once per launch)
  rope_table_kernel<<<512, 256, 0, stream>>>(ct, st);

  // 1. h1 = rmsnorm(x) -> split
  rmsnorm_split_kernel<<<4096, 256, 0, stream>>>(x, w_norm1, ah, al);
  // 2. qkv = h1 @ w_qkv + b  (f32 out)
  splitT_kernel<<<dim3(192, 64), dim3(32, 8), 0, stream>>>(w_qkv, wth, wtl,
                                                           2048, 6144);
  mgemm_kernel<0><<<dim3(48, 32), 256, 0, stream>>>(
      ah, al, wth, wtl, b_qkv, nullptr, qkvb, nullptr, nullptr, 6144, 2048);
  // 3. RoPE
  rope_apply_kernel<<<16384, 256, 0, stream>>>(qkvb, ct, st);
  // 4. y = attention -> split (reuses act region; h1 dead)
  attn_kernel<<<dim3(32, 32), 256, 0, stream>>>(qkvb, ah, al);
  // 5. x2 = x + y @ w_proj + b  -> d_out
  splitT_kernel<<<dim3(64, 64), dim3(32, 8), 0, stream>>>(w_proj, wth, wtl,
                                                          2048, 2048);
  mgemm_kernel<1><<<dim3(16, 32), 256, 0, stream>>>(
      ah, al, wth, wtl, b_proj, x, out, nullptr, nullptr, 2048, 2048);
  // 6. h2 = rmsnorm(x2) -> split (y dead)
  rmsnorm_split_kernel<<<4096, 256, 0, stream>>>(out, w_norm2, ah, al);
  // 7. f = silu(h2 @ w_fc1 + b) -> split bf16 (qkv region dead)
  splitT_kernel<<<dim3(256, 64), dim3(32, 8), 0, stream>>>(w_fc1, wth, wtl,
                                                           2048, 8192);
  mgemm_kernel<2><<<dim3(64, 32), 256, 0, stream>>>(
      ah, al, wth, wtl, b_fc1, nullptr, nullptr, fc1h, fc1l, 8192, 2048);
  // 8. out = x2 + f @ w_fc2 + b  (in-place residual, same-thread r-then-w)
  splitT_kernel<<<dim3(64, 256), dim3(32, 8), 0, stream>>>(w_fc2, wth, wtl,
                                                           8192, 2048);
  mgemm_kernel<1><<<dim3(16, 32), 256, 0, stream>>>(
      fc1h, fc1l, wth, wtl, b_fc2, out, out, nullptr, nullptr, 2048, 8192);
}

// Round 4
// 2382.651 us; speedup vs baseline: 3.0581x; 1.5752x over previous
//
#include <hip/hip_runtime.h>
#include <math.h>

typedef unsigned short u16;
typedef unsigned int u32;
typedef __attribute__((ext_vector_type(8))) short short8v;
typedef __attribute__((ext_vector_type(4))) float float4v;

#define T_SEQ 2048
#define D_MODEL 2048
#define N_HEADS 16
#define EPSV 1e-6f
#define MROWS 4096
#define MB (1024ull * 1024ull)

// ---------------- small helpers ----------------
__device__ __forceinline__ u16 f2bf(float f) {  // RNE float -> bf16 bits
  union { float f; u32 u; } v; v.f = f;
  u32 r = v.u + 0x7fffu + ((v.u >> 16) & 1u);
  return (u16)(r >> 16);
}
__device__ __forceinline__ float bf2f(u16 h) {
  union { u32 u; float f; } v; v.u = ((u32)h) << 16;
  return v.f;
}
__device__ __forceinline__ void gl16(const void* g, void* l) {
  __builtin_amdgcn_global_load_lds(
      (const __attribute__((address_space(1))) void*)g,
      (__attribute__((address_space(3))) void*)l, 16, 0, 0);
}

// ---------------------------------------------------------------------------
// RMSNorm -> split bf16 (hi, lo). One block per row.
// ---------------------------------------------------------------------------
__global__ __launch_bounds__(256) void rmsnorm_split_kernel(
    const float* __restrict__ x, const float* __restrict__ w,
    u16* __restrict__ oh, u16* __restrict__ ol) {
  const int row = blockIdx.x;
  const float* xr = x + (size_t)row * D_MODEL;

  float ss = 0.f;
#pragma unroll
  for (int it = 0; it < 2; ++it) {
    int i = threadIdx.x + it * 256;
    float4 v = ((const float4*)xr)[i];
    ss += v.x * v.x + v.y * v.y + v.z * v.z + v.w * v.w;
  }
#pragma unroll
  for (int off = 32; off >= 1; off >>= 1) ss += __shfl_xor(ss, off, 64);
  __shared__ float red[4];
  if ((threadIdx.x & 63) == 0) red[threadIdx.x >> 6] = ss;
  __syncthreads();
  const float tot = red[0] + red[1] + red[2] + red[3];
  const float n = sqrtf(tot) * 0.022097086912079608f;
  const float inv = 1.0f / (n + EPSV);

  u16* ohr = oh + (size_t)row * D_MODEL;
  u16* olr = ol + (size_t)row * D_MODEL;
#pragma unroll
  for (int it = 0; it < 2; ++it) {
    int i = threadIdx.x + it * 256;
    float4 v = ((const float4*)xr)[i];
    float4 wv = ((const float4*)w)[i];
    float o[4] = {v.x * inv * wv.x, v.y * inv * wv.y, v.z * inv * wv.z,
                  v.w * inv * wv.w};
    ushort4 h4, l4;
    h4.x = f2bf(o[0]); l4.x = f2bf(o[0] - bf2f(h4.x));
    h4.y = f2bf(o[1]); l4.y = f2bf(o[1] - bf2f(h4.y));
    h4.z = f2bf(o[2]); l4.z = f2bf(o[2] - bf2f(h4.z));
    h4.w = f2bf(o[3]); l4.w = f2bf(o[3] - bf2f(h4.w));
    ((ushort4*)ohr)[i] = h4;
    ((ushort4*)olr)[i] = l4;
  }
}

// ---------------------------------------------------------------------------
// Weight split + transpose: W[K][N] f32 -> Th[N][K], Tl[N][K] bf16
// ---------------------------------------------------------------------------
__global__ __launch_bounds__(256) void splitT_kernel(
    const float* __restrict__ W, u16* __restrict__ Th, u16* __restrict__ Tl,
    int K, int N) {
  __shared__ float tile[32][33];
  const int tx = threadIdx.x, ty = threadIdx.y;
  const int n0 = blockIdx.x * 32, k0 = blockIdx.y * 32;
#pragma unroll
  for (int i = 0; i < 4; ++i)
    tile[ty + i * 8][tx] = W[(size_t)(k0 + ty + i * 8) * N + n0 + tx];
  __syncthreads();
#pragma unroll
  for (int i = 0; i < 4; ++i) {
    const float v = tile[tx][ty + i * 8];
    const int n = n0 + ty + i * 8, k = k0 + tx;
    const u16 h = f2bf(v);
    Th[(size_t)n * K + k] = h;
    Tl[(size_t)n * K + k] = f2bf(v - bf2f(h));
  }
}

// ---------------------------------------------------------------------------
// Split-bf16 MFMA GEMM (proven R2).
// ---------------------------------------------------------------------------
template <int OUT>
__global__ __launch_bounds__(256) void mgemm_kernel(
    const u16* __restrict__ Ah, const u16* __restrict__ Al,
    const u16* __restrict__ Bh, const u16* __restrict__ Bl,
    const float* __restrict__ bias, const float* __restrict__ res,
    float* __restrict__ C, u16* __restrict__ Ch, u16* __restrict__ Cl,
    int N, int K) {
  __shared__ u16 LA[2][4096];
  __shared__ u16 LB[2][4096];

  const int tid = threadIdx.x;
  const int lane = tid & 63;
  const int wv = tid >> 6;
  const int wr = wv >> 1, wc = wv & 1;
  const int bm = blockIdx.y, bn = blockIdx.x;

  const int srow = lane >> 2;
  const int scol = (lane & 3) << 3;
  const int c0 = wv * 2, c1 = c0 + 1;

  const size_t aoff0 = (size_t)(bm * 128 + c0 * 16 + srow) * K + scol;
  const size_t aoff1 = (size_t)(bm * 128 + c1 * 16 + srow) * K + scol;
  const size_t boff0 = (size_t)(bn * 128 + c0 * 16 + srow) * K + scol;
  const size_t boff1 = (size_t)(bn * 128 + c1 * 16 + srow) * K + scol;

  const u16* APH[3] = {Ah, Al, Ah};
  const u16* BPH[3] = {Bh, Bh, Bl};
  const int S = K >> 5;
  const int S3 = 3 * S;

  float4v acc[4][4];
  const float4v zf = {0.f, 0.f, 0.f, 0.f};
#pragma unroll
  for (int i = 0; i < 4; ++i)
#pragma unroll
    for (int j = 0; j < 4; ++j) acc[i][j] = zf;

  auto STAGE = [&](int buf, int step) {
    const int ph = (step >= S) + (step >= 2 * S);
    const size_t kk = (size_t)(step - ph * S) << 5;
    const u16* ab = APH[ph];
    const u16* bb = BPH[ph];
    gl16(ab + aoff0 + kk, &LA[buf][c0 << 9]);
    gl16(ab + aoff1 + kk, &LA[buf][c1 << 9]);
    gl16(bb + boff0 + kk, &LB[buf][c0 << 9]);
    gl16(bb + boff1 + kk, &LB[buf][c1 << 9]);
  };

  const int l15 = lane & 15;
  const int kq = lane >> 4;
  const int aoffc = (wr * 64 + l15) * 32 + kq * 8;
  const int boffc = (wc * 64 + l15) * 32 + kq * 8;

  auto COMPUTE = [&](int buf) {
    short8v bfr[4];
#pragma unroll
    for (int ni = 0; ni < 4; ++ni)
      bfr[ni] = *(const short8v*)&LB[buf][boffc + ni * 512];
#pragma unroll
    for (int mi = 0; mi < 4; ++mi) {
      const short8v afr = *(const short8v*)&LA[buf][aoffc + mi * 512];
#pragma unroll
      for (int ni = 0; ni < 4; ++ni)
        acc[mi][ni] = __builtin_amdgcn_mfma_f32_16x16x32_bf16(
            afr, bfr[ni], acc[mi][ni], 0, 0, 0);
    }
  };

  STAGE(0, 0);
  __syncthreads();
  for (int step = 0; step < S3 - 1; ++step) {
    const int cur = step & 1;
    STAGE(cur ^ 1, step + 1);
    COMPUTE(cur);
    __syncthreads();
  }
  COMPUTE((S3 - 1) & 1);

  const int rsub = kq * 4;
#pragma unroll
  for (int mi = 0; mi < 4; ++mi) {
#pragma unroll
    for (int ni = 0; ni < 4; ++ni) {
      const int col = bn * 128 + wc * 64 + ni * 16 + l15;
      const float bb = bias[col];
      const float4v v = acc[mi][ni];
#pragma unroll
      for (int r = 0; r < 4; ++r) {
        const int row = bm * 128 + wr * 64 + mi * 16 + rsub + r;
        float val = v[r] + bb;
        if (OUT == 1) val += res[(size_t)row * N + col];
        if (OUT == 2) {
          const float sv = val / (1.f + expf(-val));
          const u16 hh = f2bf(sv);
          Ch[(size_t)row * N + col] = hh;
          Cl[(size_t)row * N + col] = f2bf(sv - bf2f(hh));
        } else {
          C[(size_t)row * N + col] = val;
        }
      }
    }
  }
}

// ---------------------------------------------------------------------------
// RoPE cos/sin table (double-precision trig once).
// ---------------------------------------------------------------------------
__global__ __launch_bounds__(256) void rope_table_kernel(
    float* __restrict__ ct, float* __restrict__ st) {
  const int p = blockIdx.x * 256 + threadIdx.x;  // 2048*64
  const int i = p & 63;
  const int t = p >> 6;
  const float ratef = (float)pow(10000.0, -(double)i / 64.0);
  const float theta = (float)t * ratef;
  ct[p] = (float)cos((double)theta);
  st[p] = (float)sin((double)theta);
}

// ---------------------------------------------------------------------------
// RoPE + split to bf16 hi/lo, head-major layouts:
//   Qh/Ql, Kh/Kl: [B,H,T,128]   Vth/Vtl: [B,H,128,T] (transposed)
// ---------------------------------------------------------------------------
__global__ __launch_bounds__(256) void rope_split_kernel(
    const float* __restrict__ qkv, const float* __restrict__ ct,
    const float* __restrict__ st, u16* __restrict__ Qh, u16* __restrict__ Ql,
    u16* __restrict__ Kh, u16* __restrict__ Kl, u16* __restrict__ Vth,
    u16* __restrict__ Vtl) {
  const int tt = blockIdx.x, bh = blockIdx.y;
  const int b = bh >> 4, h = bh & 15;
  const int tid = threadIdx.x;
  const int tl = tid >> 2, quad = tid & 3;
  const int t = tt * 64 + tl;
  const size_t rowbase = ((size_t)(b * T_SEQ + t)) * 6144 + h * 128;
  const size_t qkbase = (size_t)bh * T_SEQ * 128 + (size_t)t * 128;

#pragma unroll
  for (int i = 0; i < 4; ++i) {
    const int d0 = quad * 4 + i * 16;  // covers [0,64)
    const float4 c4 = *(const float4*)&ct[(size_t)t * 64 + d0];
    const float4 s4 = *(const float4*)&st[(size_t)t * 64 + d0];
#pragma unroll
    for (int qk = 0; qk < 2; ++qk) {
      const size_t src = rowbase + qk * D_MODEL + d0;
      const float4 a = *(const float4*)&qkv[src];
      const float4 bb = *(const float4*)&qkv[src + 64];
      float o1[4] = {a.x * c4.x - bb.x * s4.x, a.y * c4.y - bb.y * s4.y,
                     a.z * c4.z - bb.z * s4.z, a.w * c4.w - bb.w * s4.w};
      float o2[4] = {a.x * s4.x + bb.x * c4.x, a.y * s4.y + bb.y * c4.y,
                     a.z * s4.z + bb.z * c4.z, a.w * s4.w + bb.w * c4.w};
      u16* dh = (qk == 0) ? Qh : Kh;
      u16* dl = (qk == 0) ? Ql : Kl;
      ushort4 h4, l4;
      h4.x = f2bf(o1[0]); l4.x = f2bf(o1[0] - bf2f(h4.x));
      h4.y = f2bf(o1[1]); l4.y = f2bf(o1[1] - bf2f(h4.y));
      h4.z = f2bf(o1[2]); l4.z = f2bf(o1[2] - bf2f(h4.z));
      h4.w = f2bf(o1[3]); l4.w = f2bf(o1[3] - bf2f(h4.w));
      *(ushort4*)&dh[qkbase + d0] = h4;
      *(ushort4*)&dl[qkbase + d0] = l4;
      h4.x = f2bf(o2[0]); l4.x = f2bf(o2[0] - bf2f(h4.x));
      h4.y = f2bf(o2[1]); l4.y = f2bf(o2[1] - bf2f(h4.y));
      h4.z = f2bf(o2[2]); l4.z = f2bf(o2[2] - bf2f(h4.z));
      h4.w = f2bf(o2[3]); l4.w = f2bf(o2[3] - bf2f(h4.w));
      *(ushort4*)&dh[qkbase + 64 + d0] = h4;
      *(ushort4*)&dl[qkbase + 64 + d0] = l4;
    }
  }

  // V transpose through LDS
  __shared__ float Lv[64][132];
#pragma unroll
  for (int i = 0; i < 8; ++i) {
    const int c0 = quad * 4 + i * 16;  // covers [0,128)
    const float4 v = *(const float4*)&qkv[rowbase + 2 * D_MODEL + c0];
    *(float4*)&Lv[tl][c0] = v;
  }
  __syncthreads();
  const int dd = tid >> 1, half = tid & 1;
  const size_t vtb =
      (size_t)bh * 128 * T_SEQ + (size_t)dd * T_SEQ + tt * 64 + half * 32;
#pragma unroll
  for (int g = 0; g < 4; ++g) {
    short8v hv, lv;
#pragma unroll
    for (int e = 0; e < 8; ++e) {
      const float v = Lv[half * 32 + g * 8 + e][dd];
      const u16 hh = f2bf(v);
      hv[e] = (short)hh;
      lv[e] = (short)f2bf(v - bf2f(hh));
    }
    *(short8v*)&Vth[vtb + g * 8] = hv;
    *(short8v*)&Vtl[vtb + g * 8] = lv;
  }
}

// ---------------------------------------------------------------------------
// Split-bf16 MFMA flash attention (causal).
// ---------------------------------------------------------------------------
__global__ __launch_bounds__(256) void attn_mfma_kernel(
    const u16* __restrict__ Qh, const u16* __restrict__ Ql,
    const u16* __restrict__ Kh, const u16* __restrict__ Kl,
    const u16* __restrict__ Vth, const u16* __restrict__ Vtl,
    u16* __restrict__ yh, u16* __restrict__ yl) {
  __shared__ __align__(16) u16 lds[4][8192];  // Kh,Kl,Vth,Vtl : 16KB each
  const int qt = blockIdx.x, bh = blockIdx.y;
  const int tid = threadIdx.x, lane = tid & 63, wv = tid >> 6;
  const int l15 = lane & 15, kq = lane >> 4;

  const size_t hQK = (size_t)bh * T_SEQ * 128;
  const size_t hVt = (size_t)bh * 128 * T_SEQ;

  // Q fragments (B-operand: lane l15 = q, kq = k-quarter)
  short8v qfh[4], qfl[4];
  {
    const size_t qb = hQK + (size_t)(qt * 64 + wv * 16 + l15) * 128 + kq * 8;
#pragma unroll
    for (int ks = 0; ks < 4; ++ks) {
      qfh[ks] = *(const short8v*)(Qh + qb + ks * 32);
      qfl[ks] = *(const short8v*)(Ql + qb + ks * 32);
    }
  }

  const float4v zf = {0.f, 0.f, 0.f, 0.f};
  float4v Oa[8];
#pragma unroll
  for (int i = 0; i < 8; ++i) Oa[i] = zf;
  float mM = -INFINITY, lS = 0.f;

  for (int kt = 0; kt <= qt; ++kt) {
    __syncthreads();  // prior tile's LDS reads complete
    if (wv < 2) {     // K arrays: contiguous 16KB tile, row=256B
      const u16* src = (wv == 0 ? Kh : Kl) + hQK + (size_t)kt * 64 * 128;
#pragma unroll
      for (int i = 0; i < 16; ++i) {
        const int off = i * 1024 + lane * 16;
        const int soff = off ^ (((off >> 8) & 7) << 4);
        gl16((const char*)src + soff, (char*)(&lds[wv][0]) + i * 1024);
      }
    } else {  // Vt arrays: 128 rows x 128B, row stride 4096B
      const u16* src = (wv == 2 ? Vth : Vtl) + hVt + (size_t)kt * 64;
#pragma unroll
      for (int i = 0; i < 16; ++i) {
        const int off = i * 1024 + lane * 16;
        const int d = off >> 7;
        const int soff = (off & 127) ^ ((d & 7) << 4);
        gl16((const char*)src + (size_t)d * 4096 + soff,
             (char*)(&lds[wv][0]) + i * 1024);
      }
    }
    __syncthreads();

    // S^T = K·Q^T : A=K (4 kcol frags), B=Q. 3-pass split.
    float4v sa[4];
#pragma unroll
    for (int i = 0; i < 4; ++i) sa[i] = zf;
#pragma unroll
    for (int ks = 0; ks < 4; ++ks) {
#pragma unroll
      for (int mf = 0; mf < 4; ++mf) {
        const int ro =
            ((mf * 16 + l15) * 256 + ks * 64 + kq * 16) ^ ((l15 & 7) << 4);
        const short8v kh = *(const short8v*)((const char*)(&lds[0][0]) + ro);
        const short8v kl = *(const short8v*)((const char*)(&lds[1][0]) + ro);
        sa[mf] = __builtin_amdgcn_mfma_f32_16x16x32_bf16(kh, qfh[ks], sa[mf], 0, 0, 0);
        sa[mf] = __builtin_amdgcn_mfma_f32_16x16x32_bf16(kl, qfh[ks], sa[mf], 0, 0, 0);
        sa[mf] = __builtin_amdgcn_mfma_f32_16x16x32_bf16(kh, qfl[ks], sa[mf], 0, 0, 0);
      }
    }

    // softmax: lane owns q = wv*16+l15, 16 scores at kcol = mf*16+kq*4+r
    const float scale = 0.08838834764831845f;
    const int qloc = wv * 16 + l15;
    float p[4][4];
    float pmax = -INFINITY;
#pragma unroll
    for (int mf = 0; mf < 4; ++mf)
#pragma unroll
      for (int r = 0; r < 4; ++r) {
        float v = sa[mf][r] * scale;
        if (kt == qt && (mf * 16 + kq * 4 + r) > qloc) v = -1e30f;
        p[mf][r] = v;
        pmax = fmaxf(pmax, v);
      }
    pmax = fmaxf(pmax, __shfl_xor(pmax, 16, 64));
    pmax = fmaxf(pmax, __shfl_xor(pmax, 32, 64));
    const float mnew = fmaxf(mM, pmax);
    const float alpha = __expf(mM - mnew);
    float rs = 0.f;
#pragma unroll
    for (int mf = 0; mf < 4; ++mf)
#pragma unroll
      for (int r = 0; r < 4; ++r) {
        const float pv = __expf(p[mf][r] - mnew);
        p[mf][r] = pv;
        rs += pv;
      }
    rs += __shfl_xor(rs, 16, 64);
    rs += __shfl_xor(rs, 32, 64);
    lS = lS * alpha + rs;
    mM = mnew;

    // rescale O (O rows are q=kq*4+r; alpha lives at lane l15=q')
    const int abase = (lane & 48) + ((lane >> 4) << 2);
    float al4[4];
#pragma unroll
    for (int r = 0; r < 4; ++r) al4[r] = __shfl(alpha, abase + r, 64);
#pragma unroll
    for (int nf = 0; nf < 8; ++nf)
#pragma unroll
      for (int r = 0; r < 4; ++r) Oa[nf][r] *= al4[r];

    // redistribute P to PV A-frags: P[q=l15][k=ks2*32+kq*8+j]
    short8v pah[2], pal[2];
#pragma unroll
    for (int ks2 = 0; ks2 < 2; ++ks2) {
#pragma unroll
      for (int j = 0; j < 8; ++j) {
        const int src = ((lane >> 4) & 1) * 32 + (j >> 2) * 16 + l15;
        const float va = __shfl(p[2 * ks2][j & 3], src, 64);
        const float vb = __shfl(p[2 * ks2 + 1][j & 3], src, 64);
        const float pj = (lane >= 32) ? vb : va;
        const u16 hh = f2bf(pj);
        pah[ks2][j] = (short)hh;
        pal[ks2][j] = (short)f2bf(pj - bf2f(hh));
      }
    }

    // PV: A=P, B=Vt rows (col n = l15). 3-pass split.
#pragma unroll
    for (int nf = 0; nf < 8; ++nf) {
#pragma unroll
      for (int ks2 = 0; ks2 < 2; ++ks2) {
        const int ro =
            ((nf * 16 + l15) * 128 + ks2 * 64 + kq * 16) ^ ((l15 & 7) << 4);
        const short8v vh = *(const short8v*)((const char*)(&lds[2][0]) + ro);
        const short8v vl = *(const short8v*)((const char*)(&lds[3][0]) + ro);
        Oa[nf] = __builtin_amdgcn_mfma_f32_16x16x32_bf16(pah[ks2], vh, Oa[nf], 0, 0, 0);
        Oa[nf] = __builtin_amdgcn_mfma_f32_16x16x32_bf16(pal[ks2], vh, Oa[nf], 0, 0, 0);
        Oa[nf] = __builtin_amdgcn_mfma_f32_16x16x32_bf16(pah[ks2], vl, Oa[nf], 0, 0, 0);
      }
    }
  }

  // epilogue: O[q=kq*4+r][n=nf*16+l15] / l[q]
  const int abase = (lane & 48) + ((lane >> 4) << 2);
  float li[4];
#pragma unroll
  for (int r = 0; r < 4; ++r) li[r] = 1.f / __shfl(lS, abase + r, 64);
  const int b = bh >> 4, h = bh & 15;
#pragma unroll
  for (int r = 0; r < 4; ++r) {
    const int t = qt * 64 + wv * 16 + kq * 4 + r;
    const size_t ob = ((size_t)(b * T_SEQ + t)) * D_MODEL + h * 128 + l15;
#pragma unroll
    for (int nf = 0; nf < 8; ++nf) {
      const float val = Oa[nf][r] * li[r];
      const u16 hh = f2bf(val);
      yh[ob + nf * 16] = hh;
      yl[ob + nf * 16] = f2bf(val - bf2f(hh));
    }
  }
}

// ---------------------------------------------------------------------------
extern "C" void kernel_launch(void* const* d_in, const int* in_sizes, int n_in,
                              void* d_out, int out_size, void* d_ws,
                              size_t ws_size, hipStream_t stream) {
  const float* x       = (const float*)d_in[0];
  const float* w_norm1 = (const float*)d_in[2];
  const float* w_qkv   = (const float*)d_in[3];
  const float* b_qkv   = (const float*)d_in[4];
  const float* w_proj  = (const float*)d_in[5];
  const float* b_proj  = (const float*)d_in[6];
  const float* w_norm2 = (const float*)d_in[7];
  const float* w_fc1   = (const float*)d_in[8];
  const float* b_fc1   = (const float*)d_in[9];
  const float* w_fc2   = (const float*)d_in[10];
  const float* b_fc2   = (const float*)d_in[11];
  float* out = (float*)d_out;

  char* wsb = (char*)d_ws;
  float* qkvb = (float*)wsb;
  u16* fc1h = (u16*)wsb;
  u16* fc1l = (u16*)(wsb + 64 * MB);
  u16* qsh = (u16*)(wsb + 96 * MB);
  u16* qsl = (u16*)(wsb + 112 * MB);
  u16* ksh = (u16*)(wsb + 128 * MB);
  u16* ksl = (u16*)(wsb + 144 * MB);
  u16* vth = (u16*)(wsb + 160 * MB);
  u16* vtl = (u16*)(wsb + 176 * MB);
  u16* wth_qkv = (u16*)(wsb + 96 * MB);
  u16* wtl_qkv = (u16*)(wsb + 120 * MB);
  u16* wth_p = (u16*)(wsb + 96 * MB);
  u16* wtl_p = (u16*)(wsb + 104 * MB);
  u16* wth_f = (u16*)(wsb + 128 * MB);
  u16* wtl_f = (u16*)(wsb + 160 * MB);
  u16* ah = (u16*)(wsb + 192 * MB);
  u16* al = (u16*)(wsb + 208 * MB);
  u16* yh = ah;
  u16* yl = al;
  float* ct = (float*)(wsb + 224 * MB);
  float* st = ct + 131072;

  rope_table_kernel<<<512, 256, 0, stream>>>(ct, st);

  rmsnorm_split_kernel<<<4096, 256, 0, stream>>>(x, w_norm1, ah, al);
  splitT_kernel<<<dim3(192, 64), dim3(32, 8), 0, stream>>>(w_qkv, wth_qkv,
                                                           wtl_qkv, 2048, 6144);
  mgemm_kernel<0><<<dim3(48, 32), 256, 0, stream>>>(
      ah, al, wth_qkv, wtl_qkv, b_qkv, nullptr, qkvb, nullptr, nullptr, 6144,
      2048);
  rope_split_kernel<<<dim3(32, 32), 256, 0, stream>>>(qkvb, ct, st, qsh, qsl,
                                                      ksh, ksl, vth, vtl);
  attn_mfma_kernel<<<dim3(32, 32), 256, 0, stream>>>(qsh, qsl, ksh, ksl, vth,
                                                     vtl, yh, yl);
  splitT_kernel<<<dim3(64, 64), dim3(32, 8), 0, stream>>>(w_proj, wth_p, wtl_p,
                                                          2048, 2048);
  mgemm_kernel<1><<<dim3(16, 32), 256, 0, stream>>>(
      yh, yl, wth_p, wtl_p, b_proj, x, out, nullptr, nullptr, 2048, 2048);
  rmsnorm_split_kernel<<<4096, 256, 0, stream>>>(out, w_norm2, ah, al);
  splitT_kernel<<<dim3(256, 64), dim3(32, 8), 0, stream>>>(w_fc1, wth_f, wtl_f,
                                                           2048, 8192);
  mgemm_kernel<2><<<dim3(64, 32), 256, 0, stream>>>(
      ah, al, wth_f, wtl_f, b_fc1, nullptr, nullptr, fc1h, fc1l, 8192, 2048);
  splitT_kernel<<<dim3(64, 256), dim3(32, 8), 0, stream>>>(w_fc2, wth_f, wtl_f,
                                                           8192, 2048);
  mgemm_kernel<1><<<dim3(16, 32), 256, 0, stream>>>(
      fc1h, fc1l, wth_f, wtl_f, b_fc2, out, out, nullptr, nullptr, 2048, 8192);
}

// Round 5
// 1836.462 us; speedup vs baseline: 3.9676x; 1.2974x over previous
//
#include <hip/hip_runtime.h>
#include <math.h>

typedef unsigned short u16;
typedef unsigned int u32;
typedef __attribute__((ext_vector_type(8))) short short8v;
typedef __attribute__((ext_vector_type(4))) float float4v;

#define T_SEQ 2048
#define D_MODEL 2048
#define N_HEADS 16
#define EPSV 1e-6f
#define MROWS 4096
#define MB (1024ull * 1024ull)

// ---------------- small helpers ----------------
__device__ __forceinline__ u16 f2bf(float f) {  // RNE float -> bf16 bits
  union { float f; u32 u; } v; v.f = f;
  u32 r = v.u + 0x7fffu + ((v.u >> 16) & 1u);
  return (u16)(r >> 16);
}
__device__ __forceinline__ float bf2f(u16 h) {
  union { u32 u; float f; } v; v.u = ((u32)h) << 16;
  return v.f;
}
__device__ __forceinline__ void gl16(const void* g, void* l) {
  __builtin_amdgcn_global_load_lds(
      (const __attribute__((address_space(1))) void*)g,
      (__attribute__((address_space(3))) void*)l, 16, 0, 0);
}

// ---------------------------------------------------------------------------
// RMSNorm -> split bf16 (hi, lo). One block per row.
// ---------------------------------------------------------------------------
__global__ __launch_bounds__(256) void rmsnorm_split_kernel(
    const float* __restrict__ x, const float* __restrict__ w,
    u16* __restrict__ oh, u16* __restrict__ ol) {
  const int row = blockIdx.x;
  const float* xr = x + (size_t)row * D_MODEL;

  float ss = 0.f;
#pragma unroll
  for (int it = 0; it < 2; ++it) {
    int i = threadIdx.x + it * 256;
    float4 v = ((const float4*)xr)[i];
    ss += v.x * v.x + v.y * v.y + v.z * v.z + v.w * v.w;
  }
#pragma unroll
  for (int off = 32; off >= 1; off >>= 1) ss += __shfl_xor(ss, off, 64);
  __shared__ float red[4];
  if ((threadIdx.x & 63) == 0) red[threadIdx.x >> 6] = ss;
  __syncthreads();
  const float tot = red[0] + red[1] + red[2] + red[3];
  const float n = sqrtf(tot) * 0.022097086912079608f;
  const float inv = 1.0f / (n + EPSV);

  u16* ohr = oh + (size_t)row * D_MODEL;
  u16* olr = ol + (size_t)row * D_MODEL;
#pragma unroll
  for (int it = 0; it < 2; ++it) {
    int i = threadIdx.x + it * 256;
    float4 v = ((const float4*)xr)[i];
    float4 wv = ((const float4*)w)[i];
    float o[4] = {v.x * inv * wv.x, v.y * inv * wv.y, v.z * inv * wv.z,
                  v.w * inv * wv.w};
    ushort4 h4, l4;
    h4.x = f2bf(o[0]); l4.x = f2bf(o[0] - bf2f(h4.x));
    h4.y = f2bf(o[1]); l4.y = f2bf(o[1] - bf2f(h4.y));
    h4.z = f2bf(o[2]); l4.z = f2bf(o[2] - bf2f(h4.z));
    h4.w = f2bf(o[3]); l4.w = f2bf(o[3] - bf2f(h4.w));
    ((ushort4*)ohr)[i] = h4;
    ((ushort4*)olr)[i] = l4;
  }
}

// ---------------------------------------------------------------------------
// Weight split + transpose: W[K][N] f32 -> Th[N][K], Tl[N][K] bf16
// ---------------------------------------------------------------------------
__global__ __launch_bounds__(256) void splitT_kernel(
    const float* __restrict__ W, u16* __restrict__ Th, u16* __restrict__ Tl,
    int K, int N) {
  __shared__ float tile[32][33];
  const int tx = threadIdx.x, ty = threadIdx.y;
  const int n0 = blockIdx.x * 32, k0 = blockIdx.y * 32;
#pragma unroll
  for (int i = 0; i < 4; ++i)
    tile[ty + i * 8][tx] = W[(size_t)(k0 + ty + i * 8) * N + n0 + tx];
  __syncthreads();
#pragma unroll
  for (int i = 0; i < 4; ++i) {
    const float v = tile[tx][ty + i * 8];
    const int n = n0 + ty + i * 8, k = k0 + tx;
    const u16 h = f2bf(v);
    Th[(size_t)n * K + k] = h;
    Tl[(size_t)n * K + k] = f2bf(v - bf2f(h));
  }
}

// ---------------------------------------------------------------------------
// Fused split-bf16 MFMA GEMM: per K-step stage Ah,Al,Bh,Bl; 48 MFMA/step.
// 128x128 tile, BK=32, 4 waves. 1-D grid with XCD swizzle + GROUP=4 bn.
// OUT: 0 = f32, 1 = f32 + residual, 2 = silu -> split bf16 (Ch, Cl)
// ---------------------------------------------------------------------------
template <int OUT>
__global__ __launch_bounds__(256) void mgemm_kernel(
    const u16* __restrict__ Ah, const u16* __restrict__ Al,
    const u16* __restrict__ Bh, const u16* __restrict__ Bl,
    const float* __restrict__ bias, const float* __restrict__ res,
    float* __restrict__ C, u16* __restrict__ Ch, u16* __restrict__ Cl,
    int N, int K) {
  __shared__ __align__(16) u16 LAH[2][4096];
  __shared__ __align__(16) u16 LAL[2][4096];
  __shared__ __align__(16) u16 LBH[2][4096];
  __shared__ __align__(16) u16 LBL[2][4096];

  const int tid = threadIdx.x;
  const int lane = tid & 63;
  const int wv = tid >> 6;
  const int wr = wv >> 1, wc = wv & 1;

  // block remap: XCD-bijective chunks, then GROUP=4 bn-major groups
  const int gx = N >> 7;       // blocks along N (16/48/64: all %4==0)
  const int nwg = gx << 5;     // x 32 row-blocks (nwg %8 == 0)
  int id = blockIdx.x;
  id = (id & 7) * (nwg >> 3) + (id >> 3);
  const int g = id >> 7, w = id & 127;  // group = 4 bn x 32 bm
  const int bn = (g << 2) + (w & 3);
  const int bm = w >> 2;

  const int srow = lane >> 2;          // 0..15
  const int scol = (lane & 3) << 3;    // 0,8,16,24
  const int c0 = wv * 2, c1 = c0 + 1;  // 16-row chunks

  const size_t aoff0 = (size_t)(bm * 128 + c0 * 16 + srow) * K + scol;
  const size_t aoff1 = (size_t)(bm * 128 + c1 * 16 + srow) * K + scol;
  const size_t boff0 = (size_t)(bn * 128 + c0 * 16 + srow) * K + scol;
  const size_t boff1 = (size_t)(bn * 128 + c1 * 16 + srow) * K + scol;

  const int S = K >> 5;

  float4v acc[4][4];
  const float4v zf = {0.f, 0.f, 0.f, 0.f};
#pragma unroll
  for (int i = 0; i < 4; ++i)
#pragma unroll
    for (int j = 0; j < 4; ++j) acc[i][j] = zf;

  auto STAGE = [&](int buf, int step) {
    const size_t kk = (size_t)step << 5;
    gl16(Ah + aoff0 + kk, &LAH[buf][c0 << 9]);
    gl16(Ah + aoff1 + kk, &LAH[buf][c1 << 9]);
    gl16(Al + aoff0 + kk, &LAL[buf][c0 << 9]);
    gl16(Al + aoff1 + kk, &LAL[buf][c1 << 9]);
    gl16(Bh + boff0 + kk, &LBH[buf][c0 << 9]);
    gl16(Bh + boff1 + kk, &LBH[buf][c1 << 9]);
    gl16(Bl + boff0 + kk, &LBL[buf][c0 << 9]);
    gl16(Bl + boff1 + kk, &LBL[buf][c1 << 9]);
  };

  const int l15 = lane & 15;
  const int kq = lane >> 4;
  const int aoffc = (wr * 64 + l15) * 32 + kq * 8;
  const int boffc = (wc * 64 + l15) * 32 + kq * 8;

  auto COMPUTE = [&](int buf) {
    short8v bh[4], bl[4];
#pragma unroll
    for (int ni = 0; ni < 4; ++ni) {
      bh[ni] = *(const short8v*)&LBH[buf][boffc + ni * 512];
      bl[ni] = *(const short8v*)&LBL[buf][boffc + ni * 512];
    }
#pragma unroll
    for (int mi = 0; mi < 4; ++mi) {
      const short8v ah = *(const short8v*)&LAH[buf][aoffc + mi * 512];
      const short8v al = *(const short8v*)&LAL[buf][aoffc + mi * 512];
#pragma unroll
      for (int ni = 0; ni < 4; ++ni) {
        acc[mi][ni] = __builtin_amdgcn_mfma_f32_16x16x32_bf16(
            ah, bh[ni], acc[mi][ni], 0, 0, 0);
        acc[mi][ni] = __builtin_amdgcn_mfma_f32_16x16x32_bf16(
            al, bh[ni], acc[mi][ni], 0, 0, 0);
        acc[mi][ni] = __builtin_amdgcn_mfma_f32_16x16x32_bf16(
            ah, bl[ni], acc[mi][ni], 0, 0, 0);
      }
    }
  };

  STAGE(0, 0);
  __syncthreads();
  for (int step = 0; step < S - 1; ++step) {
    const int cur = step & 1;
    STAGE(cur ^ 1, step + 1);
    COMPUTE(cur);
    __syncthreads();
  }
  COMPUTE((S - 1) & 1);

  const int rsub = kq * 4;
#pragma unroll
  for (int mi = 0; mi < 4; ++mi) {
#pragma unroll
    for (int ni = 0; ni < 4; ++ni) {
      const int col = bn * 128 + wc * 64 + ni * 16 + l15;
      const float bb = bias[col];
      const float4v v = acc[mi][ni];
#pragma unroll
      for (int r = 0; r < 4; ++r) {
        const int row = bm * 128 + wr * 64 + mi * 16 + rsub + r;
        float val = v[r] + bb;
        if (OUT == 1) val += res[(size_t)row * N + col];
        if (OUT == 2) {
          const float sv = val / (1.f + expf(-val));
          const u16 hh = f2bf(sv);
          Ch[(size_t)row * N + col] = hh;
          Cl[(size_t)row * N + col] = f2bf(sv - bf2f(hh));
        } else {
          C[(size_t)row * N + col] = val;
        }
      }
    }
  }
}

// ---------------------------------------------------------------------------
// RoPE cos/sin table (double-precision trig once).
// ---------------------------------------------------------------------------
__global__ __launch_bounds__(256) void rope_table_kernel(
    float* __restrict__ ct, float* __restrict__ st) {
  const int p = blockIdx.x * 256 + threadIdx.x;  // 2048*64
  const int i = p & 63;
  const int t = p >> 6;
  const float ratef = (float)pow(10000.0, -(double)i / 64.0);
  const float theta = (float)t * ratef;
  ct[p] = (float)cos((double)theta);
  st[p] = (float)sin((double)theta);
}

// ---------------------------------------------------------------------------
// RoPE + split to bf16 hi/lo, head-major layouts:
//   Qh/Ql, Kh/Kl: [B,H,T,128]   Vth/Vtl: [B,H,128,T] (transposed)
// ---------------------------------------------------------------------------
__global__ __launch_bounds__(256) void rope_split_kernel(
    const float* __restrict__ qkv, const float* __restrict__ ct,
    const float* __restrict__ st, u16* __restrict__ Qh, u16* __restrict__ Ql,
    u16* __restrict__ Kh, u16* __restrict__ Kl, u16* __restrict__ Vth,
    u16* __restrict__ Vtl) {
  const int tt = blockIdx.x, bh = blockIdx.y;
  const int b = bh >> 4, h = bh & 15;
  const int tid = threadIdx.x;
  const int tl = tid >> 2, quad = tid & 3;
  const int t = tt * 64 + tl;
  const size_t rowbase = ((size_t)(b * T_SEQ + t)) * 6144 + h * 128;
  const size_t qkbase = (size_t)bh * T_SEQ * 128 + (size_t)t * 128;

#pragma unroll
  for (int i = 0; i < 4; ++i) {
    const int d0 = quad * 4 + i * 16;  // covers [0,64)
    const float4 c4 = *(const float4*)&ct[(size_t)t * 64 + d0];
    const float4 s4 = *(const float4*)&st[(size_t)t * 64 + d0];
#pragma unroll
    for (int qk = 0; qk < 2; ++qk) {
      const size_t src = rowbase + qk * D_MODEL + d0;
      const float4 a = *(const float4*)&qkv[src];
      const float4 bb = *(const float4*)&qkv[src + 64];
      float o1[4] = {a.x * c4.x - bb.x * s4.x, a.y * c4.y - bb.y * s4.y,
                     a.z * c4.z - bb.z * s4.z, a.w * c4.w - bb.w * s4.w};
      float o2[4] = {a.x * s4.x + bb.x * c4.x, a.y * s4.y + bb.y * c4.y,
                     a.z * s4.z + bb.z * c4.z, a.w * s4.w + bb.w * c4.w};
      u16* dh = (qk == 0) ? Qh : Kh;
      u16* dl = (qk == 0) ? Ql : Kl;
      ushort4 h4, l4;
      h4.x = f2bf(o1[0]); l4.x = f2bf(o1[0] - bf2f(h4.x));
      h4.y = f2bf(o1[1]); l4.y = f2bf(o1[1] - bf2f(h4.y));
      h4.z = f2bf(o1[2]); l4.z = f2bf(o1[2] - bf2f(h4.z));
      h4.w = f2bf(o1[3]); l4.w = f2bf(o1[3] - bf2f(h4.w));
      *(ushort4*)&dh[qkbase + d0] = h4;
      *(ushort4*)&dl[qkbase + d0] = l4;
      h4.x = f2bf(o2[0]); l4.x = f2bf(o2[0] - bf2f(h4.x));
      h4.y = f2bf(o2[1]); l4.y = f2bf(o2[1] - bf2f(h4.y));
      h4.z = f2bf(o2[2]); l4.z = f2bf(o2[2] - bf2f(h4.z));
      h4.w = f2bf(o2[3]); l4.w = f2bf(o2[3] - bf2f(h4.w));
      *(ushort4*)&dh[qkbase + 64 + d0] = h4;
      *(ushort4*)&dl[qkbase + 64 + d0] = l4;
    }
  }

  // V transpose through LDS
  __shared__ float Lv[64][132];
#pragma unroll
  for (int i = 0; i < 8; ++i) {
    const int c0 = quad * 4 + i * 16;  // covers [0,128)
    const float4 v = *(const float4*)&qkv[rowbase + 2 * D_MODEL + c0];
    *(float4*)&Lv[tl][c0] = v;
  }
  __syncthreads();
  const int dd = tid >> 1, half = tid & 1;
  const size_t vtb =
      (size_t)bh * 128 * T_SEQ + (size_t)dd * T_SEQ + tt * 64 + half * 32;
#pragma unroll
  for (int g = 0; g < 4; ++g) {
    short8v hv, lv;
#pragma unroll
    for (int e = 0; e < 8; ++e) {
      const float v = Lv[half * 32 + g * 8 + e][dd];
      const u16 hh = f2bf(v);
      hv[e] = (short)hh;
      lv[e] = (short)f2bf(v - bf2f(hh));
    }
    *(short8v*)&Vth[vtb + g * 8] = hv;
    *(short8v*)&Vtl[vtb + g * 8] = lv;
  }
}

// ---------------------------------------------------------------------------
// Split-bf16 MFMA flash attention (causal). 1-D grid, XCD-swizzled.
// ---------------------------------------------------------------------------
__global__ __launch_bounds__(256) void attn_mfma_kernel(
    const u16* __restrict__ Qh, const u16* __restrict__ Ql,
    const u16* __restrict__ Kh, const u16* __restrict__ Kl,
    const u16* __restrict__ Vth, const u16* __restrict__ Vtl,
    u16* __restrict__ yh, u16* __restrict__ yl) {
  __shared__ __align__(16) u16 lds[4][8192];  // Kh,Kl,Vth,Vtl : 16KB each
  int id = blockIdx.x;  // 1024 blocks
  id = (id & 7) * 128 + (id >> 3);
  const int qt = id & 31, bh = id >> 5;
  const int tid = threadIdx.x, lane = tid & 63, wv = tid >> 6;
  const int l15 = lane & 15, kq = lane >> 4;

  const size_t hQK = (size_t)bh * T_SEQ * 128;
  const size_t hVt = (size_t)bh * 128 * T_SEQ;

  // Q fragments (B-operand: lane l15 = q, kq = k-quarter)
  short8v qfh[4], qfl[4];
  {
    const size_t qb = hQK + (size_t)(qt * 64 + wv * 16 + l15) * 128 + kq * 8;
#pragma unroll
    for (int ks = 0; ks < 4; ++ks) {
      qfh[ks] = *(const short8v*)(Qh + qb + ks * 32);
      qfl[ks] = *(const short8v*)(Ql + qb + ks * 32);
    }
  }

  const float4v zf = {0.f, 0.f, 0.f, 0.f};
  float4v Oa[8];
#pragma unroll
  for (int i = 0; i < 8; ++i) Oa[i] = zf;
  float mM = -INFINITY, lS = 0.f;

  for (int kt = 0; kt <= qt; ++kt) {
    __syncthreads();  // prior tile's LDS reads complete
    if (wv < 2) {     // K arrays: contiguous 16KB tile, row=256B
      const u16* src = (wv == 0 ? Kh : Kl) + hQK + (size_t)kt * 64 * 128;
#pragma unroll
      for (int i = 0; i < 16; ++i) {
        const int off = i * 1024 + lane * 16;
        const int soff = off ^ (((off >> 8) & 7) << 4);
        gl16((const char*)src + soff, (char*)(&lds[wv][0]) + i * 1024);
      }
    } else {  // Vt arrays: 128 rows x 128B, row stride 4096B
      const u16* src = (wv == 2 ? Vth : Vtl) + hVt + (size_t)kt * 64;
#pragma unroll
      for (int i = 0; i < 16; ++i) {
        const int off = i * 1024 + lane * 16;
        const int d = off >> 7;
        const int soff = (off & 127) ^ ((d & 7) << 4);
        gl16((const char*)src + (size_t)d * 4096 + soff,
             (char*)(&lds[wv][0]) + i * 1024);
      }
    }
    __syncthreads();

    // S^T = K·Q^T : A=K (4 kcol frags), B=Q. 3-pass split.
    float4v sa[4];
#pragma unroll
    for (int i = 0; i < 4; ++i) sa[i] = zf;
#pragma unroll
    for (int ks = 0; ks < 4; ++ks) {
#pragma unroll
      for (int mf = 0; mf < 4; ++mf) {
        const int ro =
            ((mf * 16 + l15) * 256 + ks * 64 + kq * 16) ^ ((l15 & 7) << 4);
        const short8v kh = *(const short8v*)((const char*)(&lds[0][0]) + ro);
        const short8v kl = *(const short8v*)((const char*)(&lds[1][0]) + ro);
        sa[mf] = __builtin_amdgcn_mfma_f32_16x16x32_bf16(kh, qfh[ks], sa[mf], 0, 0, 0);
        sa[mf] = __builtin_amdgcn_mfma_f32_16x16x32_bf16(kl, qfh[ks], sa[mf], 0, 0, 0);
        sa[mf] = __builtin_amdgcn_mfma_f32_16x16x32_bf16(kh, qfl[ks], sa[mf], 0, 0, 0);
      }
    }

    // softmax: lane owns q = wv*16+l15, 16 scores at kcol = mf*16+kq*4+r
    const float scale = 0.08838834764831845f;
    const int qloc = wv * 16 + l15;
    float p[4][4];
    float pmax = -INFINITY;
#pragma unroll
    for (int mf = 0; mf < 4; ++mf)
#pragma unroll
      for (int r = 0; r < 4; ++r) {
        float v = sa[mf][r] * scale;
        if (kt == qt && (mf * 16 + kq * 4 + r) > qloc) v = -1e30f;
        p[mf][r] = v;
        pmax = fmaxf(pmax, v);
      }
    pmax = fmaxf(pmax, __shfl_xor(pmax, 16, 64));
    pmax = fmaxf(pmax, __shfl_xor(pmax, 32, 64));
    const float mnew = fmaxf(mM, pmax);
    const float alpha = __expf(mM - mnew);
    float rs = 0.f;
#pragma unroll
    for (int mf = 0; mf < 4; ++mf)
#pragma unroll
      for (int r = 0; r < 4; ++r) {
        const float pv = __expf(p[mf][r] - mnew);
        p[mf][r] = pv;
        rs += pv;
      }
    rs += __shfl_xor(rs, 16, 64);
    rs += __shfl_xor(rs, 32, 64);
    lS = lS * alpha + rs;
    mM = mnew;

    // rescale O (O rows are q=kq*4+r; alpha lives at lane l15=q')
    const int abase = (lane & 48) + ((lane >> 4) << 2);
    float al4[4];
#pragma unroll
    for (int r = 0; r < 4; ++r) al4[r] = __shfl(alpha, abase + r, 64);
#pragma unroll
    for (int nf = 0; nf < 8; ++nf)
#pragma unroll
      for (int r = 0; r < 4; ++r) Oa[nf][r] *= al4[r];

    // redistribute P to PV A-frags: P[q=l15][k=ks2*32+kq*8+j]
    short8v pah[2], pal[2];
#pragma unroll
    for (int ks2 = 0; ks2 < 2; ++ks2) {
#pragma unroll
      for (int j = 0; j < 8; ++j) {
        const int src = ((lane >> 4) & 1) * 32 + (j >> 2) * 16 + l15;
        const float va = __shfl(p[2 * ks2][j & 3], src, 64);
        const float vb = __shfl(p[2 * ks2 + 1][j & 3], src, 64);
        const float pj = (lane >= 32) ? vb : va;
        const u16 hh = f2bf(pj);
        pah[ks2][j] = (short)hh;
        pal[ks2][j] = (short)f2bf(pj - bf2f(hh));
      }
    }

    // PV: A=P, B=Vt rows (col n = l15). 3-pass split.
#pragma unroll
    for (int nf = 0; nf < 8; ++nf) {
#pragma unroll
      for (int ks2 = 0; ks2 < 2; ++ks2) {
        const int ro =
            ((nf * 16 + l15) * 128 + ks2 * 64 + kq * 16) ^ ((l15 & 7) << 4);
        const short8v vh = *(const short8v*)((const char*)(&lds[2][0]) + ro);
        const short8v vl = *(const short8v*)((const char*)(&lds[3][0]) + ro);
        Oa[nf] = __builtin_amdgcn_mfma_f32_16x16x32_bf16(pah[ks2], vh, Oa[nf], 0, 0, 0);
        Oa[nf] = __builtin_amdgcn_mfma_f32_16x16x32_bf16(pal[ks2], vh, Oa[nf], 0, 0, 0);
        Oa[nf] = __builtin_amdgcn_mfma_f32_16x16x32_bf16(pah[ks2], vl, Oa[nf], 0, 0, 0);
      }
    }
  }

  // epilogue: O[q=kq*4+r][n=nf*16+l15] / l[q]
  const int abase = (lane & 48) + ((lane >> 4) << 2);
  float li[4];
#pragma unroll
  for (int r = 0; r < 4; ++r) li[r] = 1.f / __shfl(lS, abase + r, 64);
  const int b = bh >> 4, h = bh & 15;
#pragma unroll
  for (int r = 0; r < 4; ++r) {
    const int t = qt * 64 + wv * 16 + kq * 4 + r;
    const size_t ob = ((size_t)(b * T_SEQ + t)) * D_MODEL + h * 128 + l15;
#pragma unroll
    for (int nf = 0; nf < 8; ++nf) {
      const float val = Oa[nf][r] * li[r];
      const u16 hh = f2bf(val);
      yh[ob + nf * 16] = hh;
      yl[ob + nf * 16] = f2bf(val - bf2f(hh));
    }
  }
}

// ---------------------------------------------------------------------------
extern "C" void kernel_launch(void* const* d_in, const int* in_sizes, int n_in,
                              void* d_out, int out_size, void* d_ws,
                              size_t ws_size, hipStream_t stream) {
  const float* x       = (const float*)d_in[0];
  const float* w_norm1 = (const float*)d_in[2];
  const float* w_qkv   = (const float*)d_in[3];
  const float* b_qkv   = (const float*)d_in[4];
  const float* w_proj  = (const float*)d_in[5];
  const float* b_proj  = (const float*)d_in[6];
  const float* w_norm2 = (const float*)d_in[7];
  const float* w_fc1   = (const float*)d_in[8];
  const float* b_fc1   = (const float*)d_in[9];
  const float* w_fc2   = (const float*)d_in[10];
  const float* b_fc2   = (const float*)d_in[11];
  float* out = (float*)d_out;

  char* wsb = (char*)d_ws;
  float* qkvb = (float*)wsb;
  u16* fc1h = (u16*)wsb;
  u16* fc1l = (u16*)(wsb + 64 * MB);
  u16* qsh = (u16*)(wsb + 96 * MB);
  u16* qsl = (u16*)(wsb + 112 * MB);
  u16* ksh = (u16*)(wsb + 128 * MB);
  u16* ksl = (u16*)(wsb + 144 * MB);
  u16* vth = (u16*)(wsb + 160 * MB);
  u16* vtl = (u16*)(wsb + 176 * MB);
  u16* wth_qkv = (u16*)(wsb + 96 * MB);
  u16* wtl_qkv = (u16*)(wsb + 120 * MB);
  u16* wth_p = (u16*)(wsb + 96 * MB);
  u16* wtl_p = (u16*)(wsb + 104 * MB);
  u16* wth_f = (u16*)(wsb + 128 * MB);
  u16* wtl_f = (u16*)(wsb + 160 * MB);
  u16* ah = (u16*)(wsb + 192 * MB);
  u16* al = (u16*)(wsb + 208 * MB);
  u16* yh = ah;
  u16* yl = al;
  float* ct = (float*)(wsb + 224 * MB);
  float* st = ct + 131072;

  rope_table_kernel<<<512, 256, 0, stream>>>(ct, st);

  rmsnorm_split_kernel<<<4096, 256, 0, stream>>>(x, w_norm1, ah, al);
  splitT_kernel<<<dim3(192, 64), dim3(32, 8), 0, stream>>>(w_qkv, wth_qkv,
                                                           wtl_qkv, 2048, 6144);
  mgemm_kernel<0><<<dim3(48 * 32), 256, 0, stream>>>(
      ah, al, wth_qkv, wtl_qkv, b_qkv, nullptr, qkvb, nullptr, nullptr, 6144,
      2048);
  rope_split_kernel<<<dim3(32, 32), 256, 0, stream>>>(qkvb, ct, st, qsh, qsl,
                                                      ksh, ksl, vth, vtl);
  attn_mfma_kernel<<<dim3(1024), 256, 0, stream>>>(qsh, qsl, ksh, ksl, vth,
                                                   vtl, yh, yl);
  splitT_kernel<<<dim3(64, 64), dim3(32, 8), 0, stream>>>(w_proj, wth_p, wtl_p,
                                                          2048, 2048);
  mgemm_kernel<1><<<dim3(16 * 32), 256, 0, stream>>>(
      yh, yl, wth_p, wtl_p, b_proj, x, out, nullptr, nullptr, 2048, 2048);
  rmsnorm_split_kernel<<<4096, 256, 0, stream>>>(out, w_norm2, ah, al);
  splitT_kernel<<<dim3(256, 64), dim3(32, 8), 0, stream>>>(w_fc1, wth_f, wtl_f,
                                                           2048, 8192);
  mgemm_kernel<2><<<dim3(64 * 32), 256, 0, stream>>>(
      ah, al, wth_f, wtl_f, b_fc1, nullptr, nullptr, fc1h, fc1l, 8192, 2048);
  splitT_kernel<<<dim3(64, 256), dim3(32, 8), 0, stream>>>(w_fc2, wth_f, wtl_f,
                                                           8192, 2048);
  mgemm_kernel<1><<<dim3(16 * 32), 256, 0, stream>>>(
      fc1h, fc1l, wth_f, wtl_f, b_fc2, out, out, nullptr, nullptr, 2048, 8192);
}

// Round 6
// 1668.649 us; speedup vs baseline: 4.3666x; 1.1006x over previous
//
#include <hip/hip_runtime.h>
#include <math.h>

typedef unsigned short u16;
typedef unsigned int u32;
typedef __attribute__((ext_vector_type(8))) short short8v;
typedef __attribute__((ext_vector_type(4))) float float4v;

#define T_SEQ 2048
#define D_MODEL 2048
#define N_HEADS 16
#define EPSV 1e-6f
#define MROWS 4096
#define MB (1024ull * 1024ull)

// ---------------- small helpers ----------------
__device__ __forceinline__ u16 f2bf(float f) {  // RNE float -> bf16 bits
  union { float f; u32 u; } v; v.f = f;
  u32 r = v.u + 0x7fffu + ((v.u >> 16) & 1u);
  return (u16)(r >> 16);
}
__device__ __forceinline__ float bf2f(u16 h) {
  union { u32 u; float f; } v; v.u = ((u32)h) << 16;
  return v.f;
}
__device__ __forceinline__ void gl16(const void* g, void* l) {
  __builtin_amdgcn_global_load_lds(
      (const __attribute__((address_space(1))) void*)g,
      (__attribute__((address_space(3))) void*)l, 16, 0, 0);
}

// ---------------------------------------------------------------------------
// RMSNorm -> split bf16 (hi, lo). One block per row.
// ---------------------------------------------------------------------------
__global__ __launch_bounds__(256) void rmsnorm_split_kernel(
    const float* __restrict__ x, const float* __restrict__ w,
    u16* __restrict__ oh, u16* __restrict__ ol) {
  const int row = blockIdx.x;
  const float* xr = x + (size_t)row * D_MODEL;

  float ss = 0.f;
#pragma unroll
  for (int it = 0; it < 2; ++it) {
    int i = threadIdx.x + it * 256;
    float4 v = ((const float4*)xr)[i];
    ss += v.x * v.x + v.y * v.y + v.z * v.z + v.w * v.w;
  }
#pragma unroll
  for (int off = 32; off >= 1; off >>= 1) ss += __shfl_xor(ss, off, 64);
  __shared__ float red[4];
  if ((threadIdx.x & 63) == 0) red[threadIdx.x >> 6] = ss;
  __syncthreads();
  const float tot = red[0] + red[1] + red[2] + red[3];
  const float n = sqrtf(tot) * 0.022097086912079608f;
  const float inv = 1.0f / (n + EPSV);

  u16* ohr = oh + (size_t)row * D_MODEL;
  u16* olr = ol + (size_t)row * D_MODEL;
#pragma unroll
  for (int it = 0; it < 2; ++it) {
    int i = threadIdx.x + it * 256;
    float4 v = ((const float4*)xr)[i];
    float4 wv = ((const float4*)w)[i];
    float o[4] = {v.x * inv * wv.x, v.y * inv * wv.y, v.z * inv * wv.z,
                  v.w * inv * wv.w};
    ushort4 h4, l4;
    h4.x = f2bf(o[0]); l4.x = f2bf(o[0] - bf2f(h4.x));
    h4.y = f2bf(o[1]); l4.y = f2bf(o[1] - bf2f(h4.y));
    h4.z = f2bf(o[2]); l4.z = f2bf(o[2] - bf2f(h4.z));
    h4.w = f2bf(o[3]); l4.w = f2bf(o[3] - bf2f(h4.w));
    ((ushort4*)ohr)[i] = h4;
    ((ushort4*)olr)[i] = l4;
  }
}

// ---------------------------------------------------------------------------
// Weight split + transpose: W[K][N] f32 -> Th[N][K], Tl[N][K] bf16
// ---------------------------------------------------------------------------
__global__ __launch_bounds__(256) void splitT_kernel(
    const float* __restrict__ W, u16* __restrict__ Th, u16* __restrict__ Tl,
    int K, int N) {
  __shared__ float tile[32][33];
  const int tx = threadIdx.x, ty = threadIdx.y;
  const int n0 = blockIdx.x * 32, k0 = blockIdx.y * 32;
#pragma unroll
  for (int i = 0; i < 4; ++i)
    tile[ty + i * 8][tx] = W[(size_t)(k0 + ty + i * 8) * N + n0 + tx];
  __syncthreads();
#pragma unroll
  for (int i = 0; i < 4; ++i) {
    const float v = tile[tx][ty + i * 8];
    const int n = n0 + ty + i * 8, k = k0 + tx;
    const u16 h = f2bf(v);
    Th[(size_t)n * K + k] = h;
    Tl[(size_t)n * K + k] = f2bf(v - bf2f(h));
  }
}

// ---------------------------------------------------------------------------
// Fused split-bf16 MFMA GEMM, counted-vmcnt pipeline.
// Tile 256x128, BK=32, 512 threads (8 waves as 4x2, per-wave 64x64).
// LDS per buffer: A rows [256][128B] (h|l interleaved slots), B [128][128B].
// XOR-swizzle byte^=((row&7)<<4) on read; staging pre-swizzles the per-lane
// GLOBAL source (slot s of row r holds G-slot s^(r&7)); gl16 dest is linear.
// Main loop: raw s_barrier + s_waitcnt vmcnt(6) (6 loads stay in flight).
// OUT: 0 = f32, 1 = f32 + residual, 2 = silu -> split bf16 (Ch, Cl)
// ---------------------------------------------------------------------------
template <int OUT>
__global__ __launch_bounds__(512) void mgemm_kernel(
    const u16* __restrict__ Ah, const u16* __restrict__ Al,
    const u16* __restrict__ Bh, const u16* __restrict__ Bl,
    const float* __restrict__ bias, const float* __restrict__ res,
    float* __restrict__ C, u16* __restrict__ Ch, u16* __restrict__ Cl,
    int N, int K) {
  __shared__ __align__(16) u16 lds[2][24576];  // 48KB per buffer

  const int tid = threadIdx.x;
  const int lane = tid & 63;
  const int wv = tid >> 6;          // 0..7
  const int wr = wv >> 1, wc = wv & 1;

  // block remap: XCD-bijective chunks, then 4-bn x 16-bm groups
  const int gx = N >> 7;            // 16/48/64 col-blocks (all %4==0)
  const int nwg = gx << 4;          // x16 row-blocks; all %8==0
  int id = blockIdx.x;
  id = (id & 7) * (nwg >> 3) + (id >> 3);
  const int g = id >> 6, w = id & 63;
  const int bn = (g << 2) + (w & 3);
  const int bm = w >> 2;            // 0..15

  // ---- staging setup (per-lane pre-swizzled global source) ----
  const int ls = lane >> 3;                 // row within 8-row chunk
  const int ss = (lane & 7) ^ ls;           // source slot after involution
  const int sel = ss >> 2;                  // 0 -> hi array, 1 -> lo array
  const int sc = (ss & 3) << 3;             // u16 col offset (0,8,16,24)

  const u16* aS[4];
  const u16* bS[2];
#pragma unroll
  for (int cc = 0; cc < 4; ++cc)
    aS[cc] = (sel ? Al : Ah) +
             (size_t)(bm * 256 + wv * 32 + cc * 8 + ls) * K + sc;
#pragma unroll
  for (int cc = 0; cc < 2; ++cc)
    bS[cc] = (sel ? Bl : Bh) +
             (size_t)(bn * 128 + wv * 16 + cc * 8 + ls) * K + sc;

  const int S = K >> 5;

  float4v acc[4][4];
  const float4v zf = {0.f, 0.f, 0.f, 0.f};
#pragma unroll
  for (int i = 0; i < 4; ++i)
#pragma unroll
    for (int j = 0; j < 4; ++j) acc[i][j] = zf;

  auto STAGE = [&](int buf, int step) {
    const int kk = step << 5;
    char* lb = (char*)&lds[buf][0];
#pragma unroll
    for (int cc = 0; cc < 4; ++cc)
      gl16(aS[cc] + kk, lb + (wv * 4 + cc) * 1024);
#pragma unroll
    for (int cc = 0; cc < 2; ++cc)
      gl16(bS[cc] + kk, lb + 32768 + (wv * 2 + cc) * 1024);
  };

  // ---- compute-side addressing (swizzled reads) ----
  const int l15 = lane & 15;
  const int kq = lane >> 4;
  const int swz = (l15 & 7) << 4;
  const int hOff = (kq * 16) ^ swz;          // hi slot byte within row
  const int lOff = (64 + kq * 16) ^ swz;     // lo slot byte within row
  int aRow[4], bRow[4];
#pragma unroll
  for (int mi = 0; mi < 4; ++mi) aRow[mi] = (wr * 64 + mi * 16 + l15) * 128;
#pragma unroll
  for (int ni = 0; ni < 4; ++ni)
    bRow[ni] = 32768 + (wc * 64 + ni * 16 + l15) * 128;

  auto COMPUTE = [&](int buf) {
    const char* lb = (const char*)&lds[buf][0];
    short8v bh[4], bl[4];
#pragma unroll
    for (int ni = 0; ni < 4; ++ni) {
      bh[ni] = *(const short8v*)(lb + bRow[ni] + hOff);
      bl[ni] = *(const short8v*)(lb + bRow[ni] + lOff);
    }
    short8v ah[4], al[4];
#pragma unroll
    for (int mi = 0; mi < 4; ++mi) {
      ah[mi] = *(const short8v*)(lb + aRow[mi] + hOff);
      al[mi] = *(const short8v*)(lb + aRow[mi] + lOff);
    }
    __builtin_amdgcn_s_setprio(1);
#pragma unroll
    for (int mi = 0; mi < 4; ++mi) {
#pragma unroll
      for (int ni = 0; ni < 4; ++ni) {
        acc[mi][ni] = __builtin_amdgcn_mfma_f32_16x16x32_bf16(
            ah[mi], bh[ni], acc[mi][ni], 0, 0, 0);
        acc[mi][ni] = __builtin_amdgcn_mfma_f32_16x16x32_bf16(
            al[mi], bh[ni], acc[mi][ni], 0, 0, 0);
        acc[mi][ni] = __builtin_amdgcn_mfma_f32_16x16x32_bf16(
            ah[mi], bl[ni], acc[mi][ni], 0, 0, 0);
      }
    }
    __builtin_amdgcn_s_setprio(0);
  };

  STAGE(0, 0);
  int t = 0;
  for (; t < S - 1; ++t) {
    STAGE((t + 1) & 1, t + 1);
    asm volatile("s_waitcnt vmcnt(6)" ::: "memory");
    __builtin_amdgcn_s_barrier();
    __builtin_amdgcn_sched_barrier(0);
    COMPUTE(t & 1);
    __builtin_amdgcn_s_barrier();
  }
  asm volatile("s_waitcnt vmcnt(0)" ::: "memory");
  __builtin_amdgcn_s_barrier();
  __builtin_amdgcn_sched_barrier(0);
  COMPUTE(t & 1);

  // ---- epilogue ----
  const int rsub = kq * 4;
#pragma unroll
  for (int mi = 0; mi < 4; ++mi) {
#pragma unroll
    for (int ni = 0; ni < 4; ++ni) {
      const int col = bn * 128 + wc * 64 + ni * 16 + l15;
      const float bb = bias[col];
      const float4v v = acc[mi][ni];
#pragma unroll
      for (int r = 0; r < 4; ++r) {
        const int row = bm * 256 + wr * 64 + mi * 16 + rsub + r;
        float val = v[r] + bb;
        if (OUT == 1) val += res[(size_t)row * N + col];
        if (OUT == 2) {
          const float sv = val / (1.f + expf(-val));
          const u16 hh = f2bf(sv);
          Ch[(size_t)row * N + col] = hh;
          Cl[(size_t)row * N + col] = f2bf(sv - bf2f(hh));
        } else {
          C[(size_t)row * N + col] = val;
        }
      }
    }
  }
}

// ---------------------------------------------------------------------------
// RoPE cos/sin table (double-precision trig once).
// ---------------------------------------------------------------------------
__global__ __launch_bounds__(256) void rope_table_kernel(
    float* __restrict__ ct, float* __restrict__ st) {
  const int p = blockIdx.x * 256 + threadIdx.x;  // 2048*64
  const int i = p & 63;
  const int t = p >> 6;
  const float ratef = (float)pow(10000.0, -(double)i / 64.0);
  const float theta = (float)t * ratef;
  ct[p] = (float)cos((double)theta);
  st[p] = (float)sin((double)theta);
}

// ---------------------------------------------------------------------------
// RoPE + split to bf16 hi/lo, head-major layouts:
//   Qh/Ql, Kh/Kl: [B,H,T,128]   Vth/Vtl: [B,H,128,T] (transposed)
// ---------------------------------------------------------------------------
__global__ __launch_bounds__(256) void rope_split_kernel(
    const float* __restrict__ qkv, const float* __restrict__ ct,
    const float* __restrict__ st, u16* __restrict__ Qh, u16* __restrict__ Ql,
    u16* __restrict__ Kh, u16* __restrict__ Kl, u16* __restrict__ Vth,
    u16* __restrict__ Vtl) {
  const int tt = blockIdx.x, bh = blockIdx.y;
  const int b = bh >> 4, h = bh & 15;
  const int tid = threadIdx.x;
  const int tl = tid >> 2, quad = tid & 3;
  const int t = tt * 64 + tl;
  const size_t rowbase = ((size_t)(b * T_SEQ + t)) * 6144 + h * 128;
  const size_t qkbase = (size_t)bh * T_SEQ * 128 + (size_t)t * 128;

#pragma unroll
  for (int i = 0; i < 4; ++i) {
    const int d0 = quad * 4 + i * 16;  // covers [0,64)
    const float4 c4 = *(const float4*)&ct[(size_t)t * 64 + d0];
    const float4 s4 = *(const float4*)&st[(size_t)t * 64 + d0];
#pragma unroll
    for (int qk = 0; qk < 2; ++qk) {
      const size_t src = rowbase + qk * D_MODEL + d0;
      const float4 a = *(const float4*)&qkv[src];
      const float4 bb = *(const float4*)&qkv[src + 64];
      float o1[4] = {a.x * c4.x - bb.x * s4.x, a.y * c4.y - bb.y * s4.y,
                     a.z * c4.z - bb.z * s4.z, a.w * c4.w - bb.w * s4.w};
      float o2[4] = {a.x * s4.x + bb.x * c4.x, a.y * s4.y + bb.y * c4.y,
                     a.z * s4.z + bb.z * c4.z, a.w * s4.w + bb.w * c4.w};
      u16* dh = (qk == 0) ? Qh : Kh;
      u16* dl = (qk == 0) ? Ql : Kl;
      ushort4 h4, l4;
      h4.x = f2bf(o1[0]); l4.x = f2bf(o1[0] - bf2f(h4.x));
      h4.y = f2bf(o1[1]); l4.y = f2bf(o1[1] - bf2f(h4.y));
      h4.z = f2bf(o1[2]); l4.z = f2bf(o1[2] - bf2f(h4.z));
      h4.w = f2bf(o1[3]); l4.w = f2bf(o1[3] - bf2f(h4.w));
      *(ushort4*)&dh[qkbase + d0] = h4;
      *(ushort4*)&dl[qkbase + d0] = l4;
      h4.x = f2bf(o2[0]); l4.x = f2bf(o2[0] - bf2f(h4.x));
      h4.y = f2bf(o2[1]); l4.y = f2bf(o2[1] - bf2f(h4.y));
      h4.z = f2bf(o2[2]); l4.z = f2bf(o2[2] - bf2f(h4.z));
      h4.w = f2bf(o2[3]); l4.w = f2bf(o2[3] - bf2f(h4.w));
      *(ushort4*)&dh[qkbase + 64 + d0] = h4;
      *(ushort4*)&dl[qkbase + 64 + d0] = l4;
    }
  }

  // V transpose through LDS
  __shared__ float Lv[64][132];
#pragma unroll
  for (int i = 0; i < 8; ++i) {
    const int c0 = quad * 4 + i * 16;  // covers [0,128)
    const float4 v = *(const float4*)&qkv[rowbase + 2 * D_MODEL + c0];
    *(float4*)&Lv[tl][c0] = v;
  }
  __syncthreads();
  const int dd = tid >> 1, half = tid & 1;
  const size_t vtb =
      (size_t)bh * 128 * T_SEQ + (size_t)dd * T_SEQ + tt * 64 + half * 32;
#pragma unroll
  for (int g = 0; g < 4; ++g) {
    short8v hv, lv;
#pragma unroll
    for (int e = 0; e < 8; ++e) {
      const float v = Lv[half * 32 + g * 8 + e][dd];
      const u16 hh = f2bf(v);
      hv[e] = (short)hh;
      lv[e] = (short)f2bf(v - bf2f(hh));
    }
    *(short8v*)&Vth[vtb + g * 8] = hv;
    *(short8v*)&Vtl[vtb + g * 8] = lv;
  }
}

// ---------------------------------------------------------------------------
// Split-bf16 MFMA flash attention (causal). 1-D grid, XCD-swizzled.
// ---------------------------------------------------------------------------
__global__ __launch_bounds__(256) void attn_mfma_kernel(
    const u16* __restrict__ Qh, const u16* __restrict__ Ql,
    const u16* __restrict__ Kh, const u16* __restrict__ Kl,
    const u16* __restrict__ Vth, const u16* __restrict__ Vtl,
    u16* __restrict__ yh, u16* __restrict__ yl) {
  __shared__ __align__(16) u16 lds[4][8192];  // Kh,Kl,Vth,Vtl : 16KB each
  int id = blockIdx.x;  // 1024 blocks
  id = (id & 7) * 128 + (id >> 3);
  const int qt = id & 31, bh = id >> 5;
  const int tid = threadIdx.x, lane = tid & 63, wv = tid >> 6;
  const int l15 = lane & 15, kq = lane >> 4;

  const size_t hQK = (size_t)bh * T_SEQ * 128;
  const size_t hVt = (size_t)bh * 128 * T_SEQ;

  // Q fragments (B-operand: lane l15 = q, kq = k-quarter)
  short8v qfh[4], qfl[4];
  {
    const size_t qb = hQK + (size_t)(qt * 64 + wv * 16 + l15) * 128 + kq * 8;
#pragma unroll
    for (int ks = 0; ks < 4; ++ks) {
      qfh[ks] = *(const short8v*)(Qh + qb + ks * 32);
      qfl[ks] = *(const short8v*)(Ql + qb + ks * 32);
    }
  }

  const float4v zf = {0.f, 0.f, 0.f, 0.f};
  float4v Oa[8];
#pragma unroll
  for (int i = 0; i < 8; ++i) Oa[i] = zf;
  float mM = -INFINITY, lS = 0.f;

  for (int kt = 0; kt <= qt; ++kt) {
    __syncthreads();  // prior tile's LDS reads complete
    if (wv < 2) {     // K arrays: contiguous 16KB tile, row=256B
      const u16* src = (wv == 0 ? Kh : Kl) + hQK + (size_t)kt * 64 * 128;
#pragma unroll
      for (int i = 0; i < 16; ++i) {
        const int off = i * 1024 + lane * 16;
        const int soff = off ^ (((off >> 8) & 7) << 4);
        gl16((const char*)src + soff, (char*)(&lds[wv][0]) + i * 1024);
      }
    } else {  // Vt arrays: 128 rows x 128B, row stride 4096B
      const u16* src = (wv == 2 ? Vth : Vtl) + hVt + (size_t)kt * 64;
#pragma unroll
      for (int i = 0; i < 16; ++i) {
        const int off = i * 1024 + lane * 16;
        const int d = off >> 7;
        const int soff = (off & 127) ^ ((d & 7) << 4);
        gl16((const char*)src + (size_t)d * 4096 + soff,
             (char*)(&lds[wv][0]) + i * 1024);
      }
    }
    __syncthreads();

    // S^T = K·Q^T : A=K (4 kcol frags), B=Q. 3-pass split.
    float4v sa[4];
#pragma unroll
    for (int i = 0; i < 4; ++i) sa[i] = zf;
#pragma unroll
    for (int ks = 0; ks < 4; ++ks) {
#pragma unroll
      for (int mf = 0; mf < 4; ++mf) {
        const int ro =
            ((mf * 16 + l15) * 256 + ks * 64 + kq * 16) ^ ((l15 & 7) << 4);
        const short8v kh = *(const short8v*)((const char*)(&lds[0][0]) + ro);
        const short8v kl = *(const short8v*)((const char*)(&lds[1][0]) + ro);
        sa[mf] = __builtin_amdgcn_mfma_f32_16x16x32_bf16(kh, qfh[ks], sa[mf], 0, 0, 0);
        sa[mf] = __builtin_amdgcn_mfma_f32_16x16x32_bf16(kl, qfh[ks], sa[mf], 0, 0, 0);
        sa[mf] = __builtin_amdgcn_mfma_f32_16x16x32_bf16(kh, qfl[ks], sa[mf], 0, 0, 0);
      }
    }

    // softmax: lane owns q = wv*16+l15, 16 scores at kcol = mf*16+kq*4+r
    const float scale = 0.08838834764831845f;
    const int qloc = wv * 16 + l15;
    float p[4][4];
    float pmax = -INFINITY;
#pragma unroll
    for (int mf = 0; mf < 4; ++mf)
#pragma unroll
      for (int r = 0; r < 4; ++r) {
        float v = sa[mf][r] * scale;
        if (kt == qt && (mf * 16 + kq * 4 + r) > qloc) v = -1e30f;
        p[mf][r] = v;
        pmax = fmaxf(pmax, v);
      }
    pmax = fmaxf(pmax, __shfl_xor(pmax, 16, 64));
    pmax = fmaxf(pmax, __shfl_xor(pmax, 32, 64));
    const float mnew = fmaxf(mM, pmax);
    const float alpha = __expf(mM - mnew);
    float rs = 0.f;
#pragma unroll
    for (int mf = 0; mf < 4; ++mf)
#pragma unroll
      for (int r = 0; r < 4; ++r) {
        const float pv = __expf(p[mf][r] - mnew);
        p[mf][r] = pv;
        rs += pv;
      }
    rs += __shfl_xor(rs, 16, 64);
    rs += __shfl_xor(rs, 32, 64);
    lS = lS * alpha + rs;
    mM = mnew;

    // rescale O (O rows are q=kq*4+r; alpha lives at lane l15=q')
    const int abase = (lane & 48) + ((lane >> 4) << 2);
    float al4[4];
#pragma unroll
    for (int r = 0; r < 4; ++r) al4[r] = __shfl(alpha, abase + r, 64);
#pragma unroll
    for (int nf = 0; nf < 8; ++nf)
#pragma unroll
      for (int r = 0; r < 4; ++r) Oa[nf][r] *= al4[r];

    // redistribute P to PV A-frags: P[q=l15][k=ks2*32+kq*8+j]
    short8v pah[2], pal[2];
#pragma unroll
    for (int ks2 = 0; ks2 < 2; ++ks2) {
#pragma unroll
      for (int j = 0; j < 8; ++j) {
        const int src = ((lane >> 4) & 1) * 32 + (j >> 2) * 16 + l15;
        const float va = __shfl(p[2 * ks2][j & 3], src, 64);
        const float vb = __shfl(p[2 * ks2 + 1][j & 3], src, 64);
        const float pj = (lane >= 32) ? vb : va;
        const u16 hh = f2bf(pj);
        pah[ks2][j] = (short)hh;
        pal[ks2][j] = (short)f2bf(pj - bf2f(hh));
      }
    }

    // PV: A=P, B=Vt rows (col n = l15). 3-pass split.
#pragma unroll
    for (int nf = 0; nf < 8; ++nf) {
#pragma unroll
      for (int ks2 = 0; ks2 < 2; ++ks2) {
        const int ro =
            ((nf * 16 + l15) * 128 + ks2 * 64 + kq * 16) ^ ((l15 & 7) << 4);
        const short8v vh = *(const short8v*)((const char*)(&lds[2][0]) + ro);
        const short8v vl = *(const short8v*)((const char*)(&lds[3][0]) + ro);
        Oa[nf] = __builtin_amdgcn_mfma_f32_16x16x32_bf16(pah[ks2], vh, Oa[nf], 0, 0, 0);
        Oa[nf] = __builtin_amdgcn_mfma_f32_16x16x32_bf16(pal[ks2], vh, Oa[nf], 0, 0, 0);
        Oa[nf] = __builtin_amdgcn_mfma_f32_16x16x32_bf16(pah[ks2], vl, Oa[nf], 0, 0, 0);
      }
    }
  }

  // epilogue: O[q=kq*4+r][n=nf*16+l15] / l[q]
  const int abase = (lane & 48) + ((lane >> 4) << 2);
  float li[4];
#pragma unroll
  for (int r = 0; r < 4; ++r) li[r] = 1.f / __shfl(lS, abase + r, 64);
  const int b = bh >> 4, h = bh & 15;
#pragma unroll
  for (int r = 0; r < 4; ++r) {
    const int t = qt * 64 + wv * 16 + kq * 4 + r;
    const size_t ob = ((size_t)(b * T_SEQ + t)) * D_MODEL + h * 128 + l15;
#pragma unroll
    for (int nf = 0; nf < 8; ++nf) {
      const float val = Oa[nf][r] * li[r];
      const u16 hh = f2bf(val);
      yh[ob + nf * 16] = hh;
      yl[ob + nf * 16] = f2bf(val - bf2f(hh));
    }
  }
}

// ---------------------------------------------------------------------------
extern "C" void kernel_launch(void* const* d_in, const int* in_sizes, int n_in,
                              void* d_out, int out_size, void* d_ws,
                              size_t ws_size, hipStream_t stream) {
  const float* x       = (const float*)d_in[0];
  const float* w_norm1 = (const float*)d_in[2];
  const float* w_qkv   = (const float*)d_in[3];
  const float* b_qkv   = (const float*)d_in[4];
  const float* w_proj  = (const float*)d_in[5];
  const float* b_proj  = (const float*)d_in[6];
  const float* w_norm2 = (const float*)d_in[7];
  const float* w_fc1   = (const float*)d_in[8];
  const float* b_fc1   = (const float*)d_in[9];
  const float* w_fc2   = (const float*)d_in[10];
  const float* b_fc2   = (const float*)d_in[11];
  float* out = (float*)d_out;

  char* wsb = (char*)d_ws;
  float* qkvb = (float*)wsb;
  u16* fc1h = (u16*)wsb;
  u16* fc1l = (u16*)(wsb + 64 * MB);
  u16* qsh = (u16*)(wsb + 96 * MB);
  u16* qsl = (u16*)(wsb + 112 * MB);
  u16* ksh = (u16*)(wsb + 128 * MB);
  u16* ksl = (u16*)(wsb + 144 * MB);
  u16* vth = (u16*)(wsb + 160 * MB);
  u16* vtl = (u16*)(wsb + 176 * MB);
  u16* wth_qkv = (u16*)(wsb + 96 * MB);
  u16* wtl_qkv = (u16*)(wsb + 120 * MB);
  u16* wth_p = (u16*)(wsb + 96 * MB);
  u16* wtl_p = (u16*)(wsb + 104 * MB);
  u16* wth_f = (u16*)(wsb + 128 * MB);
  u16* wtl_f = (u16*)(wsb + 160 * MB);
  u16* ah = (u16*)(wsb + 192 * MB);
  u16* al = (u16*)(wsb + 208 * MB);
  u16* yh = ah;
  u16* yl = al;
  float* ct = (float*)(wsb + 224 * MB);
  float* st = ct + 131072;

  rope_table_kernel<<<512, 256, 0, stream>>>(ct, st);

  rmsnorm_split_kernel<<<4096, 256, 0, stream>>>(x, w_norm1, ah, al);
  splitT_kernel<<<dim3(192, 64), dim3(32, 8), 0, stream>>>(w_qkv, wth_qkv,
                                                           wtl_qkv, 2048, 6144);
  mgemm_kernel<0><<<dim3(48 * 16), 512, 0, stream>>>(
      ah, al, wth_qkv, wtl_qkv, b_qkv, nullptr, qkvb, nullptr, nullptr, 6144,
      2048);
  rope_split_kernel<<<dim3(32, 32), 256, 0, stream>>>(qkvb, ct, st, qsh, qsl,
                                                      ksh, ksl, vth, vtl);
  attn_mfma_kernel<<<dim3(1024), 256, 0, stream>>>(qsh, qsl, ksh, ksl, vth,
                                                   vtl, yh, yl);
  splitT_kernel<<<dim3(64, 64), dim3(32, 8), 0, stream>>>(w_proj, wth_p, wtl_p,
                                                          2048, 2048);
  mgemm_kernel<1><<<dim3(16 * 16), 512, 0, stream>>>(
      yh, yl, wth_p, wtl_p, b_proj, x, out, nullptr, nullptr, 2048, 2048);
  rmsnorm_split_kernel<<<4096, 256, 0, stream>>>(out, w_norm2, ah, al);
  splitT_kernel<<<dim3(256, 64), dim3(32, 8), 0, stream>>>(w_fc1, wth_f, wtl_f,
                                                           2048, 8192);
  mgemm_kernel<2><<<dim3(64 * 16), 512, 0, stream>>>(
      ah, al, wth_f, wtl_f, b_fc1, nullptr, nullptr, fc1h, fc1l, 8192, 2048);
  splitT_kernel<<<dim3(64, 256), dim3(32, 8), 0, stream>>>(w_fc2, wth_f, wtl_f,
                                                           8192, 2048);
  mgemm_kernel<1><<<dim3(16 * 16), 512, 0, stream>>>(
      fc1h, fc1l, wth_f, wtl_f, b_fc2, out, out, nullptr, nullptr, 2048, 8192);
}

// Round 7
// 1641.614 us; speedup vs baseline: 4.4385x; 1.0165x over previous
//
#include <hip/hip_runtime.h>
#include <math.h>

typedef unsigned short u16;
typedef unsigned int u32;
typedef __attribute__((ext_vector_type(8))) short short8v;
typedef __attribute__((ext_vector_type(4))) float float4v;

#define T_SEQ 2048
#define D_MODEL 2048
#define N_HEADS 16
#define EPSV 1e-6f
#define MROWS 4096
#define MB (1024ull * 1024ull)

// ---------------- small helpers ----------------
__device__ __forceinline__ u16 f2bf(float f) {  // RNE float -> bf16 bits
  union { float f; u32 u; } v; v.f = f;
  u32 r = v.u + 0x7fffu + ((v.u >> 16) & 1u);
  return (u16)(r >> 16);
}
__device__ __forceinline__ float bf2f(u16 h) {
  union { u32 u; float f; } v; v.u = ((u32)h) << 16;
  return v.f;
}
__device__ __forceinline__ void gl16(const void* g, void* l) {
  __builtin_amdgcn_global_load_lds(
      (const __attribute__((address_space(1))) void*)g,
      (__attribute__((address_space(3))) void*)l, 16, 0, 0);
}

// ---------------------------------------------------------------------------
// RMSNorm -> split bf16 (hi, lo). One block per row.
// ---------------------------------------------------------------------------
__global__ __launch_bounds__(256) void rmsnorm_split_kernel(
    const float* __restrict__ x, const float* __restrict__ w,
    u16* __restrict__ oh, u16* __restrict__ ol) {
  const int row = blockIdx.x;
  const float* xr = x + (size_t)row * D_MODEL;

  float ss = 0.f;
#pragma unroll
  for (int it = 0; it < 2; ++it) {
    int i = threadIdx.x + it * 256;
    float4 v = ((const float4*)xr)[i];
    ss += v.x * v.x + v.y * v.y + v.z * v.z + v.w * v.w;
  }
#pragma unroll
  for (int off = 32; off >= 1; off >>= 1) ss += __shfl_xor(ss, off, 64);
  __shared__ float red[4];
  if ((threadIdx.x & 63) == 0) red[threadIdx.x >> 6] = ss;
  __syncthreads();
  const float tot = red[0] + red[1] + red[2] + red[3];
  const float n = sqrtf(tot) * 0.022097086912079608f;
  const float inv = 1.0f / (n + EPSV);

  u16* ohr = oh + (size_t)row * D_MODEL;
  u16* olr = ol + (size_t)row * D_MODEL;
#pragma unroll
  for (int it = 0; it < 2; ++it) {
    int i = threadIdx.x + it * 256;
    float4 v = ((const float4*)xr)[i];
    float4 wv = ((const float4*)w)[i];
    float o[4] = {v.x * inv * wv.x, v.y * inv * wv.y, v.z * inv * wv.z,
                  v.w * inv * wv.w};
    ushort4 h4, l4;
    h4.x = f2bf(o[0]); l4.x = f2bf(o[0] - bf2f(h4.x));
    h4.y = f2bf(o[1]); l4.y = f2bf(o[1] - bf2f(h4.y));
    h4.z = f2bf(o[2]); l4.z = f2bf(o[2] - bf2f(h4.z));
    h4.w = f2bf(o[3]); l4.w = f2bf(o[3] - bf2f(h4.w));
    ((ushort4*)ohr)[i] = h4;
    ((ushort4*)olr)[i] = l4;
  }
}

// ---------------------------------------------------------------------------
// Weight split + transpose: W[K][N] f32 -> Th[N][K], Tl[N][K] bf16
// ---------------------------------------------------------------------------
__global__ __launch_bounds__(256) void splitT_kernel(
    const float* __restrict__ W, u16* __restrict__ Th, u16* __restrict__ Tl,
    int K, int N) {
  __shared__ float tile[32][33];
  const int tx = threadIdx.x, ty = threadIdx.y;
  const int n0 = blockIdx.x * 32, k0 = blockIdx.y * 32;
#pragma unroll
  for (int i = 0; i < 4; ++i)
    tile[ty + i * 8][tx] = W[(size_t)(k0 + ty + i * 8) * N + n0 + tx];
  __syncthreads();
#pragma unroll
  for (int i = 0; i < 4; ++i) {
    const float v = tile[tx][ty + i * 8];
    const int n = n0 + ty + i * 8, k = k0 + tx;
    const u16 h = f2bf(v);
    Th[(size_t)n * K + k] = h;
    Tl[(size_t)n * K + k] = f2bf(v - bf2f(h));
  }
}

// ---------------------------------------------------------------------------
// Fused split-bf16 MFMA GEMM, phase-interleaved counted-vmcnt pipeline.
// Tile 256x128, BK=32, 512 threads (8 waves as 4x2, per-wave 64x64).
// Per K-step: 4 phases (one per ni), each {ds_read || gl16 -> barrier ->
// setprio 12 MFMA -> barrier}; vmcnt(2) at top (2 next-tile loads already
// issued -> stage(t) drained, never 0 until the final step).
// LDS XOR-swizzle byte^=((row&7)<<4), staged via pre-swizzled global source.
// OUT: 0 = f32, 1 = f32 + residual, 2 = silu -> split bf16 (Ch, Cl)
// ---------------------------------------------------------------------------
template <int OUT>
__global__ __launch_bounds__(512) void mgemm_kernel(
    const u16* __restrict__ Ah, const u16* __restrict__ Al,
    const u16* __restrict__ Bh, const u16* __restrict__ Bl,
    const float* __restrict__ bias, const float* __restrict__ res,
    float* __restrict__ C, u16* __restrict__ Ch, u16* __restrict__ Cl,
    int N, int K) {
  __shared__ __align__(16) u16 lds[2][24576];  // 48KB per buffer

  const int tid = threadIdx.x;
  const int lane = tid & 63;
  const int wv = tid >> 6;          // 0..7
  const int wr = wv >> 1, wc = wv & 1;

  // block remap: XCD-bijective chunks, then 4-bn x 16-bm groups
  const int gx = N >> 7;            // 16/48/64 col-blocks (all %4==0)
  const int nwg = gx << 4;          // x16 row-blocks; all %8==0
  int id = blockIdx.x;
  id = (id & 7) * (nwg >> 3) + (id >> 3);
  const int g = id >> 6, w = id & 63;
  const int bn = (g << 2) + (w & 3);
  const int bm = w >> 2;            // 0..15

  // ---- staging setup (per-lane pre-swizzled global source) ----
  const int ls = lane >> 3;                 // row within 8-row chunk
  const int ss = (lane & 7) ^ ls;           // source slot after involution
  const int sel = ss >> 2;                  // 0 -> hi array, 1 -> lo array
  const int sc = (ss & 3) << 3;             // u16 col offset (0,8,16,24)

  const u16* aS[4];
  const u16* bS[2];
#pragma unroll
  for (int cc = 0; cc < 4; ++cc)
    aS[cc] = (sel ? Al : Ah) +
             (size_t)(bm * 256 + wv * 32 + cc * 8 + ls) * K + sc;
#pragma unroll
  for (int cc = 0; cc < 2; ++cc)
    bS[cc] = (sel ? Bl : Bh) +
             (size_t)(bn * 128 + wv * 16 + cc * 8 + ls) * K + sc;

  const int S = K >> 5;

  float4v acc[4][4];
  const float4v zf = {0.f, 0.f, 0.f, 0.f};
#pragma unroll
  for (int i = 0; i < 4; ++i)
#pragma unroll
    for (int j = 0; j < 4; ++j) acc[i][j] = zf;

  // ---- compute-side addressing (swizzled reads) ----
  const int l15 = lane & 15;
  const int kq = lane >> 4;
  const int swz = (l15 & 7) << 4;
  const int hOff = (kq * 16) ^ swz;          // hi slot byte within row
  const int lOff = (64 + kq * 16) ^ swz;     // lo slot byte within row
  int aRow[4], bRow[4];
#pragma unroll
  for (int mi = 0; mi < 4; ++mi) aRow[mi] = (wr * 64 + mi * 16 + l15) * 128;
#pragma unroll
  for (int ni = 0; ni < 4; ++ni)
    bRow[ni] = 32768 + (wc * 64 + ni * 16 + l15) * 128;

  // prologue: stage tile 0 fully
  {
    char* lb = (char*)&lds[0][0];
#pragma unroll
    for (int cc = 0; cc < 4; ++cc) gl16(aS[cc], lb + (wv * 4 + cc) * 1024);
#pragma unroll
    for (int cc = 0; cc < 2; ++cc)
      gl16(bS[cc], lb + 32768 + (wv * 2 + cc) * 1024);
  }

  for (int t = 0; t < S; ++t) {
    const int c = t & 1;
    const char* lb = (const char*)&lds[c][0];
    char* sb = (char*)&lds[c ^ 1][0];
    const bool pre = (t + 1 < S);
    const int kk = (t + 1) << 5;

    // ---- top: issue first 2 next-tile loads, then wait current tile ----
    if (pre) {
      gl16(aS[0] + kk, sb + (wv * 4 + 0) * 1024);
      gl16(aS[1] + kk, sb + (wv * 4 + 1) * 1024);
      asm volatile("s_waitcnt vmcnt(2)" ::: "memory");
    } else {
      asm volatile("s_waitcnt vmcnt(0)" ::: "memory");
    }
    __builtin_amdgcn_s_barrier();
    __builtin_amdgcn_sched_barrier(0);

    // ---- P0: read all A frags + b0; stage A23 ----
    short8v ah[4], al[4];
#pragma unroll
    for (int mi = 0; mi < 4; ++mi) {
      ah[mi] = *(const short8v*)(lb + aRow[mi] + hOff);
      al[mi] = *(const short8v*)(lb + aRow[mi] + lOff);
    }
    short8v bh = *(const short8v*)(lb + bRow[0] + hOff);
    short8v bl = *(const short8v*)(lb + bRow[0] + lOff);
    if (pre) {
      gl16(aS[2] + kk, sb + (wv * 4 + 2) * 1024);
      gl16(aS[3] + kk, sb + (wv * 4 + 3) * 1024);
    }
    __builtin_amdgcn_s_barrier();
    __builtin_amdgcn_sched_barrier(0);
    __builtin_amdgcn_s_setprio(1);
#pragma unroll
    for (int mi = 0; mi < 4; ++mi) {
      acc[mi][0] = __builtin_amdgcn_mfma_f32_16x16x32_bf16(ah[mi], bh,
                                                           acc[mi][0], 0, 0, 0);
      acc[mi][0] = __builtin_amdgcn_mfma_f32_16x16x32_bf16(al[mi], bh,
                                                           acc[mi][0], 0, 0, 0);
      acc[mi][0] = __builtin_amdgcn_mfma_f32_16x16x32_bf16(ah[mi], bl,
                                                           acc[mi][0], 0, 0, 0);
    }
    __builtin_amdgcn_s_setprio(0);
    __builtin_amdgcn_s_barrier();
    __builtin_amdgcn_sched_barrier(0);

    // ---- P1..P3: read b[ni]; P1 stages B01 ----
#pragma unroll
    for (int ni = 1; ni < 4; ++ni) {
      bh = *(const short8v*)(lb + bRow[ni] + hOff);
      bl = *(const short8v*)(lb + bRow[ni] + lOff);
      if (ni == 1 && pre) {
        gl16(bS[0] + kk, sb + 32768 + (wv * 2 + 0) * 1024);
        gl16(bS[1] + kk, sb + 32768 + (wv * 2 + 1) * 1024);
      }
      __builtin_amdgcn_s_barrier();
      __builtin_amdgcn_sched_barrier(0);
      __builtin_amdgcn_s_setprio(1);
#pragma unroll
      for (int mi = 0; mi < 4; ++mi) {
        acc[mi][ni] = __builtin_amdgcn_mfma_f32_16x16x32_bf16(
            ah[mi], bh, acc[mi][ni], 0, 0, 0);
        acc[mi][ni] = __builtin_amdgcn_mfma_f32_16x16x32_bf16(
            al[mi], bh, acc[mi][ni], 0, 0, 0);
        acc[mi][ni] = __builtin_amdgcn_mfma_f32_16x16x32_bf16(
            ah[mi], bl, acc[mi][ni], 0, 0, 0);
      }
      __builtin_amdgcn_s_setprio(0);
      __builtin_amdgcn_s_barrier();
      __builtin_amdgcn_sched_barrier(0);
    }
  }

  // ---- epilogue ----
  const int rsub = kq * 4;
#pragma unroll
  for (int mi = 0; mi < 4; ++mi) {
#pragma unroll
    for (int ni = 0; ni < 4; ++ni) {
      const int col = bn * 128 + wc * 64 + ni * 16 + l15;
      const float bb = bias[col];
      const float4v v = acc[mi][ni];
#pragma unroll
      for (int r = 0; r < 4; ++r) {
        const int row = bm * 256 + wr * 64 + mi * 16 + rsub + r;
        float val = v[r] + bb;
        if (OUT == 1) val += res[(size_t)row * N + col];
        if (OUT == 2) {
          const float sv = val / (1.f + expf(-val));
          const u16 hh = f2bf(sv);
          Ch[(size_t)row * N + col] = hh;
          Cl[(size_t)row * N + col] = f2bf(sv - bf2f(hh));
        } else {
          C[(size_t)row * N + col] = val;
        }
      }
    }
  }
}

// ---------------------------------------------------------------------------
// RoPE cos/sin table (double-precision trig once).
// ---------------------------------------------------------------------------
__global__ __launch_bounds__(256) void rope_table_kernel(
    float* __restrict__ ct, float* __restrict__ st) {
  const int p = blockIdx.x * 256 + threadIdx.x;  // 2048*64
  const int i = p & 63;
  const int t = p >> 6;
  const float ratef = (float)pow(10000.0, -(double)i / 64.0);
  const float theta = (float)t * ratef;
  ct[p] = (float)cos((double)theta);
  st[p] = (float)sin((double)theta);
}

// ---------------------------------------------------------------------------
// RoPE + split to bf16 hi/lo, head-major layouts:
//   Qh/Ql, Kh/Kl: [B,H,T,128]   Vth/Vtl: [B,H,128,T] (transposed)
// ---------------------------------------------------------------------------
__global__ __launch_bounds__(256) void rope_split_kernel(
    const float* __restrict__ qkv, const float* __restrict__ ct,
    const float* __restrict__ st, u16* __restrict__ Qh, u16* __restrict__ Ql,
    u16* __restrict__ Kh, u16* __restrict__ Kl, u16* __restrict__ Vth,
    u16* __restrict__ Vtl) {
  const int tt = blockIdx.x, bh = blockIdx.y;
  const int b = bh >> 4, h = bh & 15;
  const int tid = threadIdx.x;
  const int tl = tid >> 2, quad = tid & 3;
  const int t = tt * 64 + tl;
  const size_t rowbase = ((size_t)(b * T_SEQ + t)) * 6144 + h * 128;
  const size_t qkbase = (size_t)bh * T_SEQ * 128 + (size_t)t * 128;

#pragma unroll
  for (int i = 0; i < 4; ++i) {
    const int d0 = quad * 4 + i * 16;  // covers [0,64)
    const float4 c4 = *(const float4*)&ct[(size_t)t * 64 + d0];
    const float4 s4 = *(const float4*)&st[(size_t)t * 64 + d0];
#pragma unroll
    for (int qk = 0; qk < 2; ++qk) {
      const size_t src = rowbase + qk * D_MODEL + d0;
      const float4 a = *(const float4*)&qkv[src];
      const float4 bb = *(const float4*)&qkv[src + 64];
      float o1[4] = {a.x * c4.x - bb.x * s4.x, a.y * c4.y - bb.y * s4.y,
                     a.z * c4.z - bb.z * s4.z, a.w * c4.w - bb.w * s4.w};
      float o2[4] = {a.x * s4.x + bb.x * c4.x, a.y * s4.y + bb.y * c4.y,
                     a.z * s4.z + bb.z * c4.z, a.w * s4.w + bb.w * c4.w};
      u16* dh = (qk == 0) ? Qh : Kh;
      u16* dl = (qk == 0) ? Ql : Kl;
      ushort4 h4, l4;
      h4.x = f2bf(o1[0]); l4.x = f2bf(o1[0] - bf2f(h4.x));
      h4.y = f2bf(o1[1]); l4.y = f2bf(o1[1] - bf2f(h4.y));
      h4.z = f2bf(o1[2]); l4.z = f2bf(o1[2] - bf2f(h4.z));
      h4.w = f2bf(o1[3]); l4.w = f2bf(o1[3] - bf2f(h4.w));
      *(ushort4*)&dh[qkbase + d0] = h4;
      *(ushort4*)&dl[qkbase + d0] = l4;
      h4.x = f2bf(o2[0]); l4.x = f2bf(o2[0] - bf2f(h4.x));
      h4.y = f2bf(o2[1]); l4.y = f2bf(o2[1] - bf2f(h4.y));
      h4.z = f2bf(o2[2]); l4.z = f2bf(o2[2] - bf2f(h4.z));
      h4.w = f2bf(o2[3]); l4.w = f2bf(o2[3] - bf2f(h4.w));
      *(ushort4*)&dh[qkbase + 64 + d0] = h4;
      *(ushort4*)&dl[qkbase + 64 + d0] = l4;
    }
  }

  // V transpose through LDS
  __shared__ float Lv[64][132];
#pragma unroll
  for (int i = 0; i < 8; ++i) {
    const int c0 = quad * 4 + i * 16;  // covers [0,128)
    const float4 v = *(const float4*)&qkv[rowbase + 2 * D_MODEL + c0];
    *(float4*)&Lv[tl][c0] = v;
  }
  __syncthreads();
  const int dd = tid >> 1, half = tid & 1;
  const size_t vtb =
      (size_t)bh * 128 * T_SEQ + (size_t)dd * T_SEQ + tt * 64 + half * 32;
#pragma unroll
  for (int g = 0; g < 4; ++g) {
    short8v hv, lv;
#pragma unroll
    for (int e = 0; e < 8; ++e) {
      const float v = Lv[half * 32 + g * 8 + e][dd];
      const u16 hh = f2bf(v);
      hv[e] = (short)hh;
      lv[e] = (short)f2bf(v - bf2f(hh));
    }
    *(short8v*)&Vth[vtb + g * 8] = hv;
    *(short8v*)&Vtl[vtb + g * 8] = lv;
  }
}

// ---------------------------------------------------------------------------
// Split-bf16 MFMA flash attention (causal). 1-D grid, XCD-swizzled.
// ---------------------------------------------------------------------------
__global__ __launch_bounds__(256) void attn_mfma_kernel(
    const u16* __restrict__ Qh, const u16* __restrict__ Ql,
    const u16* __restrict__ Kh, const u16* __restrict__ Kl,
    const u16* __restrict__ Vth, const u16* __restrict__ Vtl,
    u16* __restrict__ yh, u16* __restrict__ yl) {
  __shared__ __align__(16) u16 lds[4][8192];  // Kh,Kl,Vth,Vtl : 16KB each
  int id = blockIdx.x;  // 1024 blocks
  id = (id & 7) * 128 + (id >> 3);
  const int qt = id & 31, bh = id >> 5;
  const int tid = threadIdx.x, lane = tid & 63, wv = tid >> 6;
  const int l15 = lane & 15, kq = lane >> 4;

  const size_t hQK = (size_t)bh * T_SEQ * 128;
  const size_t hVt = (size_t)bh * 128 * T_SEQ;

  // Q fragments (B-operand: lane l15 = q, kq = k-quarter)
  short8v qfh[4], qfl[4];
  {
    const size_t qb = hQK + (size_t)(qt * 64 + wv * 16 + l15) * 128 + kq * 8;
#pragma unroll
    for (int ks = 0; ks < 4; ++ks) {
      qfh[ks] = *(const short8v*)(Qh + qb + ks * 32);
      qfl[ks] = *(const short8v*)(Ql + qb + ks * 32);
    }
  }

  const float4v zf = {0.f, 0.f, 0.f, 0.f};
  float4v Oa[8];
#pragma unroll
  for (int i = 0; i < 8; ++i) Oa[i] = zf;
  float mM = -INFINITY, lS = 0.f;

  for (int kt = 0; kt <= qt; ++kt) {
    __syncthreads();  // prior tile's LDS reads complete
    if (wv < 2) {     // K arrays: contiguous 16KB tile, row=256B
      const u16* src = (wv == 0 ? Kh : Kl) + hQK + (size_t)kt * 64 * 128;
#pragma unroll
      for (int i = 0; i < 16; ++i) {
        const int off = i * 1024 + lane * 16;
        const int soff = off ^ (((off >> 8) & 7) << 4);
        gl16((const char*)src + soff, (char*)(&lds[wv][0]) + i * 1024);
      }
    } else {  // Vt arrays: 128 rows x 128B, row stride 4096B
      const u16* src = (wv == 2 ? Vth : Vtl) + hVt + (size_t)kt * 64;
#pragma unroll
      for (int i = 0; i < 16; ++i) {
        const int off = i * 1024 + lane * 16;
        const int d = off >> 7;
        const int soff = (off & 127) ^ ((d & 7) << 4);
        gl16((const char*)src + (size_t)d * 4096 + soff,
             (char*)(&lds[wv][0]) + i * 1024);
      }
    }
    __syncthreads();

    // S^T = K·Q^T : A=K (4 kcol frags), B=Q. 3-pass split.
    float4v sa[4];
#pragma unroll
    for (int i = 0; i < 4; ++i) sa[i] = zf;
#pragma unroll
    for (int ks = 0; ks < 4; ++ks) {
#pragma unroll
      for (int mf = 0; mf < 4; ++mf) {
        const int ro =
            ((mf * 16 + l15) * 256 + ks * 64 + kq * 16) ^ ((l15 & 7) << 4);
        const short8v kh = *(const short8v*)((const char*)(&lds[0][0]) + ro);
        const short8v kl = *(const short8v*)((const char*)(&lds[1][0]) + ro);
        sa[mf] = __builtin_amdgcn_mfma_f32_16x16x32_bf16(kh, qfh[ks], sa[mf], 0, 0, 0);
        sa[mf] = __builtin_amdgcn_mfma_f32_16x16x32_bf16(kl, qfh[ks], sa[mf], 0, 0, 0);
        sa[mf] = __builtin_amdgcn_mfma_f32_16x16x32_bf16(kh, qfl[ks], sa[mf], 0, 0, 0);
      }
    }

    // softmax: lane owns q = wv*16+l15, 16 scores at kcol = mf*16+kq*4+r
    const float scale = 0.08838834764831845f;
    const int qloc = wv * 16 + l15;
    float p[4][4];
    float pmax = -INFINITY;
#pragma unroll
    for (int mf = 0; mf < 4; ++mf)
#pragma unroll
      for (int r = 0; r < 4; ++r) {
        float v = sa[mf][r] * scale;
        if (kt == qt && (mf * 16 + kq * 4 + r) > qloc) v = -1e30f;
        p[mf][r] = v;
        pmax = fmaxf(pmax, v);
      }
    pmax = fmaxf(pmax, __shfl_xor(pmax, 16, 64));
    pmax = fmaxf(pmax, __shfl_xor(pmax, 32, 64));
    const float mnew = fmaxf(mM, pmax);
    const float alpha = __expf(mM - mnew);
    float rs = 0.f;
#pragma unroll
    for (int mf = 0; mf < 4; ++mf)
#pragma unroll
      for (int r = 0; r < 4; ++r) {
        const float pv = __expf(p[mf][r] - mnew);
        p[mf][r] = pv;
        rs += pv;
      }
    rs += __shfl_xor(rs, 16, 64);
    rs += __shfl_xor(rs, 32, 64);
    lS = lS * alpha + rs;
    mM = mnew;

    // rescale O (O rows are q=kq*4+r; alpha lives at lane l15=q')
    const int abase = (lane & 48) + ((lane >> 4) << 2);
    float al4[4];
#pragma unroll
    for (int r = 0; r < 4; ++r) al4[r] = __shfl(alpha, abase + r, 64);
#pragma unroll
    for (int nf = 0; nf < 8; ++nf)
#pragma unroll
      for (int r = 0; r < 4; ++r) Oa[nf][r] *= al4[r];

    // redistribute P to PV A-frags: P[q=l15][k=ks2*32+kq*8+j]
    short8v pah[2], pal[2];
#pragma unroll
    for (int ks2 = 0; ks2 < 2; ++ks2) {
#pragma unroll
      for (int j = 0; j < 8; ++j) {
        const int src = ((lane >> 4) & 1) * 32 + (j >> 2) * 16 + l15;
        const float va = __shfl(p[2 * ks2][j & 3], src, 64);
        const float vb = __shfl(p[2 * ks2 + 1][j & 3], src, 64);
        const float pj = (lane >= 32) ? vb : va;
        const u16 hh = f2bf(pj);
        pah[ks2][j] = (short)hh;
        pal[ks2][j] = (short)f2bf(pj - bf2f(hh));
      }
    }

    // PV: A=P, B=Vt rows (col n = l15). 3-pass split.
#pragma unroll
    for (int nf = 0; nf < 8; ++nf) {
#pragma unroll
      for (int ks2 = 0; ks2 < 2; ++ks2) {
        const int ro =
            ((nf * 16 + l15) * 128 + ks2 * 64 + kq * 16) ^ ((l15 & 7) << 4);
        const short8v vh = *(const short8v*)((const char*)(&lds[2][0]) + ro);
        const short8v vl = *(const short8v*)((const char*)(&lds[3][0]) + ro);
        Oa[nf] = __builtin_amdgcn_mfma_f32_16x16x32_bf16(pah[ks2], vh, Oa[nf], 0, 0, 0);
        Oa[nf] = __builtin_amdgcn_mfma_f32_16x16x32_bf16(pal[ks2], vh, Oa[nf], 0, 0, 0);
        Oa[nf] = __builtin_amdgcn_mfma_f32_16x16x32_bf16(pah[ks2], vl, Oa[nf], 0, 0, 0);
      }
    }
  }

  // epilogue: O[q=kq*4+r][n=nf*16+l15] / l[q]
  const int abase = (lane & 48) + ((lane >> 4) << 2);
  float li[4];
#pragma unroll
  for (int r = 0; r < 4; ++r) li[r] = 1.f / __shfl(lS, abase + r, 64);
  const int b = bh >> 4, h = bh & 15;
#pragma unroll
  for (int r = 0; r < 4; ++r) {
    const int t = qt * 64 + wv * 16 + kq * 4 + r;
    const size_t ob = ((size_t)(b * T_SEQ + t)) * D_MODEL + h * 128 + l15;
#pragma unroll
    for (int nf = 0; nf < 8; ++nf) {
      const float val = Oa[nf][r] * li[r];
      const u16 hh = f2bf(val);
      yh[ob + nf * 16] = hh;
      yl[ob + nf * 16] = f2bf(val - bf2f(hh));
    }
  }
}

// ---------------------------------------------------------------------------
extern "C" void kernel_launch(void* const* d_in, const int* in_sizes, int n_in,
                              void* d_out, int out_size, void* d_ws,
                              size_t ws_size, hipStream_t stream) {
  const float* x       = (const float*)d_in[0];
  const float* w_norm1 = (const float*)d_in[2];
  const float* w_qkv   = (const float*)d_in[3];
  const float* b_qkv   = (const float*)d_in[4];
  const float* w_proj  = (const float*)d_in[5];
  const float* b_proj  = (const float*)d_in[6];
  const float* w_norm2 = (const float*)d_in[7];
  const float* w_fc1   = (const float*)d_in[8];
  const float* b_fc1   = (const float*)d_in[9];
  const float* w_fc2   = (const float*)d_in[10];
  const float* b_fc2   = (const float*)d_in[11];
  float* out = (float*)d_out;

  char* wsb = (char*)d_ws;
  float* qkvb = (float*)wsb;
  u16* fc1h = (u16*)wsb;
  u16* fc1l = (u16*)(wsb + 64 * MB);
  u16* qsh = (u16*)(wsb + 96 * MB);
  u16* qsl = (u16*)(wsb + 112 * MB);
  u16* ksh = (u16*)(wsb + 128 * MB);
  u16* ksl = (u16*)(wsb + 144 * MB);
  u16* vth = (u16*)(wsb + 160 * MB);
  u16* vtl = (u16*)(wsb + 176 * MB);
  u16* wth_qkv = (u16*)(wsb + 96 * MB);
  u16* wtl_qkv = (u16*)(wsb + 120 * MB);
  u16* wth_p = (u16*)(wsb + 96 * MB);
  u16* wtl_p = (u16*)(wsb + 104 * MB);
  u16* wth_f = (u16*)(wsb + 128 * MB);
  u16* wtl_f = (u16*)(wsb + 160 * MB);
  u16* ah = (u16*)(wsb + 192 * MB);
  u16* al = (u16*)(wsb + 208 * MB);
  u16* yh = ah;
  u16* yl = al;
  float* ct = (float*)(wsb + 224 * MB);
  float* st = ct + 131072;

  rope_table_kernel<<<512, 256, 0, stream>>>(ct, st);

  rmsnorm_split_kernel<<<4096, 256, 0, stream>>>(x, w_norm1, ah, al);
  splitT_kernel<<<dim3(192, 64), dim3(32, 8), 0, stream>>>(w_qkv, wth_qkv,
                                                           wtl_qkv, 2048, 6144);
  mgemm_kernel<0><<<dim3(48 * 16), 512, 0, stream>>>(
      ah, al, wth_qkv, wtl_qkv, b_qkv, nullptr, qkvb, nullptr, nullptr, 6144,
      2048);
  rope_split_kernel<<<dim3(32, 32), 256, 0, stream>>>(qkvb, ct, st, qsh, qsl,
                                                      ksh, ksl, vth, vtl);
  attn_mfma_kernel<<<dim3(1024), 256, 0, stream>>>(qsh, qsl, ksh, ksl, vth,
                                                   vtl, yh, yl);
  splitT_kernel<<<dim3(64, 64), dim3(32, 8), 0, stream>>>(w_proj, wth_p, wtl_p,
                                                          2048, 2048);
  mgemm_kernel<1><<<dim3(16 * 16), 512, 0, stream>>>(
      yh, yl, wth_p, wtl_p, b_proj, x, out, nullptr, nullptr, 2048, 2048);
  rmsnorm_split_kernel<<<4096, 256, 0, stream>>>(out, w_norm2, ah, al);
  splitT_kernel<<<dim3(256, 64), dim3(32, 8), 0, stream>>>(w_fc1, wth_f, wtl_f,
                                                           2048, 8192);
  mgemm_kernel<2><<<dim3(64 * 16), 512, 0, stream>>>(
      ah, al, wth_f, wtl_f, b_fc1, nullptr, nullptr, fc1h, fc1l, 8192, 2048);
  splitT_kernel<<<dim3(64, 256), dim3(32, 8), 0, stream>>>(w_fc2, wth_f, wtl_f,
                                                           8192, 2048);
  mgemm_kernel<1><<<dim3(16 * 16), 512, 0, stream>>>(
      fc1h, fc1l, wth_f, wtl_f, b_fc2, out, out, nullptr, nullptr, 2048, 8192);
}